// Round 7
// baseline (672.802 us; speedup 1.0000x reference)
//
#include <hip/hip_runtime.h>
#include <hip/hip_bf16.h>
#include <math.h>

typedef unsigned int uint;
typedef __bf16 bf16_t;
typedef bf16_t bf16x8 __attribute__((ext_vector_type(8)));
typedef float f32x4 __attribute__((ext_vector_type(4)));

__device__ inline float2 bf2_unpack(uint u) {
    union { uint i; float f; } a, b;
    a.i = u << 16;
    b.i = u & 0xffff0000u;
    return make_float2(a.f, b.f);
}

__device__ inline uint bf2_pack(float x, float y) {
    __hip_bfloat162 h;
    h.x = __float2bfloat16(x);
    h.y = __float2bfloat16(y);
    return *(uint*)&h;
}

__device__ inline void store_out(float* p, float v) { *p = v; }
__device__ inline void store_out(__hip_bfloat16* p, float v) { *p = __float2bfloat16(v); }

// ---------------- CSR build ----------------
__global__ __launch_bounds__(256) void k_count(const int* __restrict__ ei, int* __restrict__ indeg, int E) {
    int e = blockIdx.x * 256 + threadIdx.x;
    if (e < E) atomicAdd(&indeg[ei[E + e]], 1);
}

// chunked scan + dinv computation fused
__global__ __launch_bounds__(1024) void k_scan(const int* __restrict__ indeg, int* __restrict__ off,
                                               float* __restrict__ dinv, int n) {
    __shared__ int tmp[1024];
    int t = threadIdx.x;
    int per = (n + 1023) >> 10;
    int s0 = t * per, s1 = s0 + per; if (s1 > n) s1 = n;
    int sum = 0;
    for (int i = s0; i < s1; ++i) sum += indeg[i];
    tmp[t] = sum;
    __syncthreads();
    for (int d = 1; d < 1024; d <<= 1) {
        int a = (t >= d) ? tmp[t - d] : 0;
        __syncthreads();
        tmp[t] += a;
        __syncthreads();
    }
    int carry = tmp[t] - sum;  // exclusive prefix
    for (int i = s0; i < s1; ++i) {
        int dg = indeg[i];
        off[i] = carry;
        carry += dg;
        dinv[i] = rsqrtf((float)(dg + 1));   // self-loop adds 1
    }
    if (t == 1023) off[n] = tmp[1023];
}

__global__ __launch_bounds__(256) void k_fill(const int* __restrict__ ei, const int* __restrict__ off,
                                              int* __restrict__ cursor, int* __restrict__ col, int E) {
    int e = blockIdx.x * 256 + threadIdx.x;
    if (e < E) {
        int d = ei[E + e];
        int p = atomicAdd(&cursor[d], 1);
        col[off[d] + p] = ei[e];
    }
}

// ---------------- fp32 -> bf16 weight conversion (6 x 128x128 mats) ----------------
__global__ __launch_bounds__(256) void k_cvt6(const float* __restrict__ s0, const float* __restrict__ s1,
                                              const float* __restrict__ s2, const float* __restrict__ s3,
                                              const float* __restrict__ s4, const float* __restrict__ s5,
                                              __hip_bfloat16* __restrict__ dst) {
    int i = blockIdx.x * 256 + threadIdx.x;
    if (i >= 6 * 16384) return;
    int m = i >> 14;
    const float* s = (m == 0) ? s0 : (m == 1) ? s1 : (m == 2) ? s2 : (m == 3) ? s3 : (m == 4) ? s4 : s5;
    dst[i] = __float2bfloat16(s[i & 16383]);
}

// ---------------- scalar linear for FI=32 (embed), bf16 out ----------------
template<int FI, bool BIAS, bool RELU, typename OUT>
__global__ __launch_bounds__(256) void k_linear(const float* __restrict__ x, const float* __restrict__ W,
                                                const float* __restrict__ b, OUT* __restrict__ y, int n) {
    __shared__ float4 Wt4[(FI / 4) * 128];
    __shared__ float4 xl[2][FI / 4];
    int t = threadIdx.x & 127;
    int h = threadIdx.x >> 7;
    {
        const float4* Wrow = (const float4*)(W + (size_t)t * FI);
        #pragma unroll
        for (int k4 = h * (FI / 8); k4 < (h + 1) * (FI / 8); ++k4) Wt4[k4 * 128 + t] = Wrow[k4];
    }
    float bias = 0.f;
    if (BIAS) bias = b[t];
    __syncthreads();
    for (int n0 = blockIdx.x * 2; n0 < n; n0 += gridDim.x * 2) {
        int nn = n0 + h;
        if (nn < n && t < FI / 4) xl[h][t] = ((const float4*)(x + (size_t)nn * FI))[t];
        __syncthreads();
        if (nn < n) {
            float acc = bias;
            #pragma unroll
            for (int k4 = 0; k4 < FI / 4; ++k4) {
                float4 xv = xl[h][k4];
                float4 wv = Wt4[k4 * 128 + t];
                acc += xv.x * wv.x + xv.y * wv.y + xv.z * wv.z + xv.w * wv.w;
            }
            if (RELU) acc = fmaxf(acc, 0.f);
            store_out(&y[(size_t)nn * 128 + t], acc);
        }
        __syncthreads();
    }
}

// ---------------- MFMA linear with per-row dinv prescale ----------------
__global__ __launch_bounds__(256) void k_lin_mfma_scale(const __hip_bfloat16* __restrict__ X,
                                                        const __hip_bfloat16* __restrict__ W,
                                                        const float* __restrict__ dinv,
                                                        __hip_bfloat16* __restrict__ y, int n) {
    int wave = threadIdx.x >> 6, lane = threadIdx.x & 63;
    int r0 = blockIdx.x * 64 + wave * 16;
    if (r0 >= n) return;
    int mrow = r0 + (lane & 15);
    if (mrow >= n) mrow = n - 1;
    int kk4 = lane >> 4;
    const bf16x8* xr = (const bf16x8*)((const bf16_t*)X + (size_t)mrow * 128);
    bf16x8 a0 = xr[0 * 4 + kk4];
    bf16x8 a1 = xr[1 * 4 + kk4];
    bf16x8 a2 = xr[2 * 4 + kk4];
    bf16x8 a3 = xr[3 * 4 + kk4];
    int orow = (lane >> 4) * 4;
    int ocol = lane & 15;
    float dv[4];
    #pragma unroll
    for (int j = 0; j < 4; ++j) {
        int row = r0 + orow + j;
        dv[j] = (row < n) ? dinv[row] : 0.f;
    }
    #pragma unroll
    for (int c = 0; c < 8; ++c) {
        const bf16x8* wr = (const bf16x8*)((const bf16_t*)W + (size_t)(c * 16 + (lane & 15)) * 128);
        bf16x8 b0 = wr[0 * 4 + kk4];
        bf16x8 b1 = wr[1 * 4 + kk4];
        bf16x8 b2 = wr[2 * 4 + kk4];
        bf16x8 b3 = wr[3 * 4 + kk4];
        f32x4 acc = {0.f, 0.f, 0.f, 0.f};
        acc = __builtin_amdgcn_mfma_f32_16x16x32_bf16(a0, b0, acc, 0, 0, 0);
        acc = __builtin_amdgcn_mfma_f32_16x16x32_bf16(a1, b1, acc, 0, 0, 0);
        acc = __builtin_amdgcn_mfma_f32_16x16x32_bf16(a2, b2, acc, 0, 0, 0);
        acc = __builtin_amdgcn_mfma_f32_16x16x32_bf16(a3, b3, acc, 0, 0, 0);
        int gcol = c * 16 + ocol;
        #pragma unroll
        for (int j = 0; j < 4; ++j) {
            int row = r0 + orow + j;
            if (row < n) store_out(&y[(size_t)row * 128 + gcol], acc[j] * dv[j]);
        }
    }
}

// ---------------- fused q/k/v/skip MFMA ----------------
// q -> Cqb bf16 (x0.25); k,v -> KV bf16 pair-interleaved [kp0 vp0 kp1 vp1 ...]; skip -> Bb bf16
__global__ __launch_bounds__(256) void k_qkvs_mfma(const __hip_bfloat16* __restrict__ X,
                                                   const __hip_bfloat16* __restrict__ W4,
                                                   const float* __restrict__ bq, const float* __restrict__ bk,
                                                   const float* __restrict__ bv, const float* __restrict__ bs,
                                                   __hip_bfloat16* __restrict__ Cqb, __hip_bfloat16* __restrict__ KV,
                                                   __hip_bfloat16* __restrict__ Bb, int n) {
    int wave = threadIdx.x >> 6, lane = threadIdx.x & 63;
    int r0 = blockIdx.x * 64 + wave * 16;
    if (r0 >= n) return;
    int mrow = r0 + (lane & 15);
    if (mrow >= n) mrow = n - 1;
    int kk4 = lane >> 4;
    const bf16x8* xr = (const bf16x8*)((const bf16_t*)X + (size_t)mrow * 128);
    bf16x8 a0 = xr[0 * 4 + kk4];
    bf16x8 a1 = xr[1 * 4 + kk4];
    bf16x8 a2 = xr[2 * 4 + kk4];
    bf16x8 a3 = xr[3 * 4 + kk4];
    int orow = (lane >> 4) * 4;
    int ocol = lane & 15;
    #pragma unroll
    for (int m = 0; m < 4; ++m) {
        const bf16_t* Wm = (const bf16_t*)W4 + (size_t)m * 16384;
        const float* bias = (m == 0) ? bq : (m == 1) ? bk : (m == 2) ? bv : bs;
        #pragma unroll
        for (int c = 0; c < 8; ++c) {
            const bf16x8* wr = (const bf16x8*)(Wm + (size_t)(c * 16 + (lane & 15)) * 128);
            bf16x8 b0 = wr[0 * 4 + kk4];
            bf16x8 b1 = wr[1 * 4 + kk4];
            bf16x8 b2 = wr[2 * 4 + kk4];
            bf16x8 b3 = wr[3 * 4 + kk4];
            f32x4 acc = {0.f, 0.f, 0.f, 0.f};
            acc = __builtin_amdgcn_mfma_f32_16x16x32_bf16(a0, b0, acc, 0, 0, 0);
            acc = __builtin_amdgcn_mfma_f32_16x16x32_bf16(a1, b1, acc, 0, 0, 0);
            acc = __builtin_amdgcn_mfma_f32_16x16x32_bf16(a2, b2, acc, 0, 0, 0);
            acc = __builtin_amdgcn_mfma_f32_16x16x32_bf16(a3, b3, acc, 0, 0, 0);
            int gcol = c * 16 + ocol;
            float bb = bias[gcol];
            int kvi = ((gcol >> 1) << 2) + (gcol & 1);   // pair-interleaved index
            #pragma unroll
            for (int j = 0; j < 4; ++j) {
                int row = r0 + orow + j;
                if (row >= n) continue;
                float v = acc[j] + bb;
                if (m == 0) store_out(&Cqb[(size_t)row * 128 + gcol], v * 0.25f);
                else if (m == 1) store_out(&KV[(size_t)row * 256 + kvi], v);
                else if (m == 2) store_out(&KV[(size_t)row * 256 + kvi + 2], v);
                else store_out(&Bb[(size_t)row * 128 + gcol], v);
            }
        }
    }
}

// ---------------- GCN aggregation: 1 wave/node, 2 edges in parallel via wave halves ----------------
// y = relu(dinv[dst] * (xw'[self] + sum_nbrs xw'[s]) + b), bf16 out. xw' prescaled by src dinv.
// half = lane>>5 processes edges i0+half, i0+half+2, ...; l32 = lane&31 covers feats 4*l32..4*l32+3.
__global__ __launch_bounds__(256) void k_gcn_agg(const uint* __restrict__ xw, const int* __restrict__ off,
                                                 const int* __restrict__ col, const float* __restrict__ dinv,
                                                 const float* __restrict__ bias, uint2* __restrict__ y, int n) {
    int wid = (blockIdx.x * 256 + threadIdx.x) >> 6;
    int lane = threadIdx.x & 63;
    int half = lane >> 5, l32 = lane & 31;
    if (wid >= n) return;
    float di = dinv[wid];
    const uint2* x2 = (const uint2*)xw;          // row = 32 uint2 (256 B)
    float a0, a1, a2, a3;
    {
        uint2 su = x2[((size_t)wid << 5) + l32];
        float2 p = bf2_unpack(su.x), r = bf2_unpack(su.y);
        if (half == 0) { a0 = p.x; a1 = p.y; a2 = r.x; a3 = r.y; }
        else { a0 = 0.f; a1 = 0.f; a2 = 0.f; a3 = 0.f; }
    }
    int i1 = off[wid + 1];
    int i = off[wid] + half;
    for (; i + 6 < i1; i += 8) {                 // 4 edges per half per iter (8 edges/wave-iter)
        int s0 = col[i], s1 = col[i + 2], s2 = col[i + 4], s3 = col[i + 6];
        uint2 u0 = x2[((size_t)s0 << 5) + l32];
        uint2 u1 = x2[((size_t)s1 << 5) + l32];
        uint2 u2 = x2[((size_t)s2 << 5) + l32];
        uint2 u3 = x2[((size_t)s3 << 5) + l32];
        float2 p0 = bf2_unpack(u0.x), r0 = bf2_unpack(u0.y);
        float2 p1 = bf2_unpack(u1.x), r1 = bf2_unpack(u1.y);
        float2 p2 = bf2_unpack(u2.x), r2 = bf2_unpack(u2.y);
        float2 p3 = bf2_unpack(u3.x), r3 = bf2_unpack(u3.y);
        a0 += (p0.x + p1.x) + (p2.x + p3.x);
        a1 += (p0.y + p1.y) + (p2.y + p3.y);
        a2 += (r0.x + r1.x) + (r2.x + r3.x);
        a3 += (r0.y + r1.y) + (r2.y + r3.y);
    }
    for (; i < i1; i += 2) {
        uint2 u0 = x2[((size_t)col[i] << 5) + l32];
        float2 p0 = bf2_unpack(u0.x), r0 = bf2_unpack(u0.y);
        a0 += p0.x; a1 += p0.y; a2 += r0.x; a3 += r0.y;
    }
    a0 += __shfl_xor(a0, 32);
    a1 += __shfl_xor(a1, 32);
    a2 += __shfl_xor(a2, 32);
    a3 += __shfl_xor(a3, 32);
    if (half == 0) {
        float4 b4 = ((const float4*)bias)[l32];
        uint o0 = bf2_pack(fmaxf(di * a0 + b4.x, 0.f), fmaxf(di * a1 + b4.y, 0.f));
        uint o1 = bf2_pack(fmaxf(di * a2 + b4.z, 0.f), fmaxf(di * a3 + b4.w, 0.f));
        y[((size_t)wid << 5) + l32] = make_uint2(o0, o1);
    }
}

// ---------------- transformer attention: 1 wave/dst, pair-interleaved KV, uint2 loads ----------------
// q bf16 prescaled by 0.25. KV row = 64 uint2: lane l -> {k feats 2l,2l+1 ; v feats 2l,2l+1}.
// head h = l>>3 spans lanes 8h..8h+7.
__global__ __launch_bounds__(256) void k_attn(const uint* __restrict__ qb, const uint2* __restrict__ kv2,
                                              const int* __restrict__ off, const int* __restrict__ col,
                                              uint* __restrict__ io, int n) {
    int wid = (blockIdx.x * 256 + threadIdx.x) >> 6;
    int lane = threadIdx.x & 63;
    if (wid >= n) return;
    float2 q2 = bf2_unpack(qb[(size_t)wid * 64 + lane]);
    float m = -INFINITY, s = 0.f;
    float2 acc = make_float2(0.f, 0.f);
    int i = off[wid], i1 = off[wid + 1];
    for (; i + 7 < i1; i += 8) {
        uint2 u0 = kv2[((size_t)col[i] << 6) + lane];
        uint2 u1 = kv2[((size_t)col[i + 1] << 6) + lane];
        uint2 u2 = kv2[((size_t)col[i + 2] << 6) + lane];
        uint2 u3 = kv2[((size_t)col[i + 3] << 6) + lane];
        uint2 u4 = kv2[((size_t)col[i + 4] << 6) + lane];
        uint2 u5 = kv2[((size_t)col[i + 5] << 6) + lane];
        uint2 u6 = kv2[((size_t)col[i + 6] << 6) + lane];
        uint2 u7 = kv2[((size_t)col[i + 7] << 6) + lane];
        float2 k0 = bf2_unpack(u0.x), k1 = bf2_unpack(u1.x), k2 = bf2_unpack(u2.x), k3 = bf2_unpack(u3.x);
        float2 k4 = bf2_unpack(u4.x), k5 = bf2_unpack(u5.x), k6 = bf2_unpack(u6.x), k7 = bf2_unpack(u7.x);
        float l0 = q2.x * k0.x + q2.y * k0.y;
        float l1 = q2.x * k1.x + q2.y * k1.y;
        float l2 = q2.x * k2.x + q2.y * k2.y;
        float l3 = q2.x * k3.x + q2.y * k3.y;
        float l4 = q2.x * k4.x + q2.y * k4.y;
        float l5 = q2.x * k5.x + q2.y * k5.y;
        float l6 = q2.x * k6.x + q2.y * k6.y;
        float l7 = q2.x * k7.x + q2.y * k7.y;
        l0 += __shfl_xor(l0, 1); l1 += __shfl_xor(l1, 1); l2 += __shfl_xor(l2, 1); l3 += __shfl_xor(l3, 1);
        l4 += __shfl_xor(l4, 1); l5 += __shfl_xor(l5, 1); l6 += __shfl_xor(l6, 1); l7 += __shfl_xor(l7, 1);
        l0 += __shfl_xor(l0, 2); l1 += __shfl_xor(l1, 2); l2 += __shfl_xor(l2, 2); l3 += __shfl_xor(l3, 2);
        l4 += __shfl_xor(l4, 2); l5 += __shfl_xor(l5, 2); l6 += __shfl_xor(l6, 2); l7 += __shfl_xor(l7, 2);
        l0 += __shfl_xor(l0, 4); l1 += __shfl_xor(l1, 4); l2 += __shfl_xor(l2, 4); l3 += __shfl_xor(l3, 4);
        l4 += __shfl_xor(l4, 4); l5 += __shfl_xor(l5, 4); l6 += __shfl_xor(l6, 4); l7 += __shfl_xor(l7, 4);
        float mx = fmaxf(fmaxf(fmaxf(l0, l1), fmaxf(l2, l3)), fmaxf(fmaxf(l4, l5), fmaxf(l6, l7)));
        if (mx > m) {                         // rescale once per 8-edge chunk
            float corr = __expf(m - mx);      // 0 on first chunk (m=-inf)
            s *= corr;
            acc.x *= corr;
            acc.y *= corr;
            m = mx;
        }
        float e0 = __expf(l0 - m), e1 = __expf(l1 - m), e2 = __expf(l2 - m), e3 = __expf(l3 - m);
        float e4 = __expf(l4 - m), e5 = __expf(l5 - m), e6 = __expf(l6 - m), e7 = __expf(l7 - m);
        s += ((e0 + e1) + (e2 + e3)) + ((e4 + e5) + (e6 + e7));
        float2 v0 = bf2_unpack(u0.y), v1 = bf2_unpack(u1.y), v2 = bf2_unpack(u2.y), v3 = bf2_unpack(u3.y);
        float2 v4 = bf2_unpack(u4.y), v5 = bf2_unpack(u5.y), v6 = bf2_unpack(u6.y), v7 = bf2_unpack(u7.y);
        acc.x += ((e0 * v0.x + e1 * v1.x) + (e2 * v2.x + e3 * v3.x)) + ((e4 * v4.x + e5 * v5.x) + (e6 * v6.x + e7 * v7.x));
        acc.y += ((e0 * v0.y + e1 * v1.y) + (e2 * v2.y + e3 * v3.y)) + ((e4 * v4.y + e5 * v5.y) + (e6 * v6.y + e7 * v7.y));
    }
    for (; i < i1; ++i) {
        uint2 u0 = kv2[((size_t)col[i] << 6) + lane];
        float2 k0 = bf2_unpack(u0.x);
        float l0 = q2.x * k0.x + q2.y * k0.y;
        l0 += __shfl_xor(l0, 1);
        l0 += __shfl_xor(l0, 2);
        l0 += __shfl_xor(l0, 4);
        if (l0 > m) {
            float corr = __expf(m - l0);
            s *= corr;
            acc.x *= corr;
            acc.y *= corr;
            m = l0;
        }
        float e0 = __expf(l0 - m);
        s += e0;
        float2 v0 = bf2_unpack(u0.y);
        acc.x += e0 * v0.x;
        acc.y += e0 * v0.y;
    }
    float inv = 1.f / fmaxf(s, 1e-16f);
    uint* orow = io + (size_t)wid * 64 + lane;
    float2 o2 = bf2_unpack(*orow);               // skip connection already there
    o2.x += acc.x * inv;
    o2.y += acc.y * inv;
    *orow = bf2_pack(o2.x, o2.y);
}

// ---------------- mean-pool per graph (batch sorted), bf16 in, 64 nodes/block ----------------
__global__ __launch_bounds__(128) void k_pool(const __hip_bfloat16* __restrict__ x, const int* __restrict__ batch,
                                              float* __restrict__ gsum, float* __restrict__ cnt, int n) {
    int t = threadIdx.x;
    int start = blockIdx.x * 64;
    int end = start + 64; if (end > n) end = n;
    if (start >= n) return;
    int cur = batch[start];
    float acc = 0.f;
    int run = 0;
    for (int nn = start; nn < end; ++nn) {
        int g = batch[nn];
        if (g != cur) {
            atomicAdd(&gsum[cur * 128 + t], acc);
            if (t == 0) atomicAdd(&cnt[cur], (float)run);
            acc = 0.f; run = 0; cur = g;
        }
        acc += __bfloat162float(x[(size_t)nn * 128 + t]);
        run++;
    }
    atomicAdd(&gsum[cur * 128 + t], acc);
    if (t == 0) atomicAdd(&cnt[cur], (float)run);
}

// ---------------- FiLM + LSTM + LayerNorm + dueling heads, one block per graph ----------------
__global__ __launch_bounds__(128) void k_final(
    const float* __restrict__ gsum, const float* __restrict__ cnt, const float* __restrict__ w,
    const float* __restrict__ Wgam, const float* __restrict__ bgam,
    const float* __restrict__ Wbet, const float* __restrict__ bbet,
    const float* __restrict__ hprev, const float* __restrict__ cprev,
    const float* __restrict__ Wih, const float* __restrict__ bih,
    const float* __restrict__ Whh, const float* __restrict__ bhh,
    const float* __restrict__ lng, const float* __restrict__ lnb,
    const float* __restrict__ Wa1, const float* __restrict__ ba1,
    const float* __restrict__ Wa2, const float* __restrict__ ba2,
    const float* __restrict__ Wv1, const float* __restrict__ bv1,
    const float* __restrict__ Wv2, const float* __restrict__ bv2,
    float* __restrict__ out_qv, float* __restrict__ out_h, float* __restrict__ out_c) {
    int g = blockIdx.x, t = threadIdx.x;
    __shared__ __align__(16) float ge[128], hp[128], hn[128], r1[128], a1s[128], red[128];
    __shared__ float adv[16], val[2], mu_s, var_s;

    float w0 = w[g * 2 + 0], w1 = w[g * 2 + 1];
    float c = fmaxf(cnt[g], 1.f);
    float mn = gsum[g * 128 + t] / c;
    float gam = w0 * Wgam[2 * t] + w1 * Wgam[2 * t + 1] + bgam[t];
    float bet = w0 * Wbet[2 * t] + w1 * Wbet[2 * t + 1] + bbet[t];
    ge[t] = (1.f + gam) * mn + bet;
    hp[t] = hprev[g * 128 + t];
    __syncthreads();

    float gi = bih[t] + bhh[t];
    float gf = bih[128 + t] + bhh[128 + t];
    float gg = bih[256 + t] + bhh[256 + t];
    float go = bih[384 + t] + bhh[384 + t];
    {
        const float4* ge4 = (const float4*)ge;
        const float4* hp4 = (const float4*)hp;
        const float4* Ai = (const float4*)(Wih + (size_t)t * 128);
        const float4* Af = (const float4*)(Wih + (size_t)(128 + t) * 128);
        const float4* Ag = (const float4*)(Wih + (size_t)(256 + t) * 128);
        const float4* Ao = (const float4*)(Wih + (size_t)(384 + t) * 128);
        const float4* Hi = (const float4*)(Whh + (size_t)t * 128);
        const float4* Hf = (const float4*)(Whh + (size_t)(128 + t) * 128);
        const float4* Hg = (const float4*)(Whh + (size_t)(256 + t) * 128);
        const float4* Ho = (const float4*)(Whh + (size_t)(384 + t) * 128);
        #pragma unroll 4
        for (int k4 = 0; k4 < 32; ++k4) {
            float4 a = ge4[k4], h4 = hp4[k4], u;
            u = Ai[k4]; gi += a.x * u.x + a.y * u.y + a.z * u.z + a.w * u.w;
            u = Hi[k4]; gi += h4.x * u.x + h4.y * u.y + h4.z * u.z + h4.w * u.w;
            u = Af[k4]; gf += a.x * u.x + a.y * u.y + a.z * u.z + a.w * u.w;
            u = Hf[k4]; gf += h4.x * u.x + h4.y * u.y + h4.z * u.z + h4.w * u.w;
            u = Ag[k4]; gg += a.x * u.x + a.y * u.y + a.z * u.z + a.w * u.w;
            u = Hg[k4]; gg += h4.x * u.x + h4.y * u.y + h4.z * u.z + h4.w * u.w;
            u = Ao[k4]; go += a.x * u.x + a.y * u.y + a.z * u.z + a.w * u.w;
            u = Ho[k4]; go += h4.x * u.x + h4.y * u.y + h4.z * u.z + h4.w * u.w;
        }
    }
    float ig = 1.f / (1.f + __expf(-gi));
    float fg = 1.f / (1.f + __expf(-gf));
    float gc = tanhf(gg);
    float og = 1.f / (1.f + __expf(-go));
    float craw = fg * cprev[g * 128 + t] + ig * gc;
    float hraw = og * tanhf(craw);
    out_c[g * 128 + t] = fminf(fmaxf(craw, -1e6f), 1e6f);

    red[t] = hraw;
    __syncthreads();
    for (int s2 = 64; s2 > 0; s2 >>= 1) { if (t < s2) red[t] += red[t + s2]; __syncthreads(); }
    if (t == 0) mu_s = red[0] * (1.f / 128.f);
    __syncthreads();
    float mu = mu_s;
    float d = hraw - mu;
    red[t] = d * d;
    __syncthreads();
    for (int s2 = 64; s2 > 0; s2 >>= 1) { if (t < s2) red[t] += red[t + s2]; __syncthreads(); }
    if (t == 0) var_s = red[0] * (1.f / 128.f);
    __syncthreads();
    float hv = d * rsqrtf(var_s + 1e-5f) * lng[t] + lnb[t];
    hn[t] = hv;
    out_h[g * 128 + t] = hv;
    __syncthreads();

    float accv = bv1[t], acca = ba1[t];
    {
        const float4* hn4 = (const float4*)hn;
        const float4* V1 = (const float4*)(Wv1 + (size_t)t * 128);
        const float4* A1 = (const float4*)(Wa1 + (size_t)t * 128);
        #pragma unroll 4
        for (int k4 = 0; k4 < 32; ++k4) {
            float4 hh = hn4[k4], u;
            u = V1[k4]; accv += hh.x * u.x + hh.y * u.y + hh.z * u.z + hh.w * u.w;
            u = A1[k4]; acca += hh.x * u.x + hh.y * u.y + hh.z * u.z + hh.w * u.w;
        }
    }
    r1[t] = fmaxf(accv, 0.f);
    a1s[t] = fmaxf(acca, 0.f);
    __syncthreads();
    if (t < 2) {
        float s = bv2[t];
        const float4* V2 = (const float4*)(Wv2 + (size_t)t * 128);
        const float4* r4 = (const float4*)r1;
        for (int k4 = 0; k4 < 32; ++k4) { float4 u = V2[k4], rr = r4[k4]; s += rr.x * u.x + rr.y * u.y + rr.z * u.z + rr.w * u.w; }
        val[t] = s;
    }
    if (t < 14) {
        float s = ba2[t];
        const float4* A2 = (const float4*)(Wa2 + (size_t)t * 128);
        const float4* a4 = (const float4*)a1s;
        for (int k4 = 0; k4 < 32; ++k4) { float4 u = A2[k4], aa = a4[k4]; s += aa.x * u.x + aa.y * u.y + aa.z * u.z + aa.w * u.w; }
        adv[t] = s;
    }
    __syncthreads();
    if (t < 14) {
        int o = t & 1;
        float mo = (adv[o] + adv[o + 2] + adv[o + 4] + adv[o + 6] + adv[o + 8] + adv[o + 10] + adv[o + 12]) * (1.f / 7.f);
        float qq = val[o] + adv[t] - mo;
        if (isnan(qq)) qq = 0.f;
        qq = fminf(fmaxf(qq, -100.f), 100.f);
        out_qv[g * 14 + t] = qq;
    }
}

extern "C" void kernel_launch(void* const* d_in, const int* in_sizes, int n_in,
                              void* d_out, int out_size, void* d_ws, size_t ws_size,
                              hipStream_t stream) {
    const float* nf    = (const float*)d_in[0];
    const int*   ei    = (const int*)d_in[1];
    const int*   batch = (const int*)d_in[2];
    const float* w     = (const float*)d_in[3];
    const float* hprev = (const float*)d_in[4];
    const float* cprev = (const float*)d_in[5];
    const float* W_emb = (const float*)d_in[6];  const float* b_emb = (const float*)d_in[7];
    const float* W_g1  = (const float*)d_in[8];  const float* b_g1  = (const float*)d_in[9];
    const float* W_g2  = (const float*)d_in[10]; const float* b_g2  = (const float*)d_in[11];
    const float* Wq    = (const float*)d_in[12]; const float* bq    = (const float*)d_in[13];
    const float* Wk    = (const float*)d_in[14]; const float* bk    = (const float*)d_in[15];
    const float* Wv    = (const float*)d_in[16]; const float* bv    = (const float*)d_in[17];
    const float* Wskip = (const float*)d_in[18]; const float* bskip = (const float*)d_in[19];
    const float* Wgam  = (const float*)d_in[20]; const float* bgam  = (const float*)d_in[21];
    const float* Wbet  = (const float*)d_in[22]; const float* bbet  = (const float*)d_in[23];
    const float* Wih   = (const float*)d_in[24]; const float* bih   = (const float*)d_in[25];
    const float* Whh   = (const float*)d_in[26]; const float* bhh   = (const float*)d_in[27];
    const float* lng   = (const float*)d_in[28]; const float* lnb   = (const float*)d_in[29];
    const float* Wa1   = (const float*)d_in[30]; const float* ba1   = (const float*)d_in[31];
    const float* Wa2   = (const float*)d_in[32]; const float* ba2   = (const float*)d_in[33];
    const float* Wv1   = (const float*)d_in[34]; const float* bv1   = (const float*)d_in[35];
    const float* Wv2   = (const float*)d_in[36]; const float* bv2   = (const float*)d_in[37];

    int N = in_sizes[2];
    int E = in_sizes[1] / 2;
    int B = in_sizes[4] / 128;

    char* p = (char*)d_ws;
    auto alloc = [&](size_t bytes) { char* r = p; p += (bytes + 511) & ~(size_t)511; return r; };
    int*   indeg  = (int*)alloc((size_t)N * 4);
    int*   cursor = (int*)alloc((size_t)N * 4);
    float* gsum   = (float*)alloc((size_t)B * 128 * 4);
    float* cnt    = (float*)alloc((size_t)B * 4);
    size_t zbytes = (size_t)(p - (char*)d_ws);   // region zeroed each call
    int*   off    = (int*)alloc((size_t)(N + 1) * 4);
    int*   col    = (int*)alloc((size_t)E * 4);
    float* dinv   = (float*)alloc((size_t)N * 4);
    __hip_bfloat16* Wc  = (__hip_bfloat16*)alloc((size_t)6 * 16384 * 2);  // bf16 weights: g1,g2,q,k,v,skip
    __hip_bfloat16* X0b = (__hip_bfloat16*)alloc((size_t)N * 128 * 2);    // x0 / x2
    __hip_bfloat16* X1b = (__hip_bfloat16*)alloc((size_t)N * 128 * 2);    // x1
    __hip_bfloat16* XWb = (__hip_bfloat16*)alloc((size_t)N * 128 * 2);    // xw scratch (prescaled)
    __hip_bfloat16* KV  = (__hip_bfloat16*)alloc((size_t)N * 256 * 2);    // pair-interleaved k|v
    __hip_bfloat16* Cqb = (__hip_bfloat16*)alloc((size_t)N * 128 * 2);    // q bf16 (x0.25)
    __hip_bfloat16* Bb  = (__hip_bfloat16*)alloc((size_t)N * 128 * 2);    // skip + attn out, bf16
    if ((size_t)(p - (char*)d_ws) > ws_size) return;

    hipMemsetAsync(d_ws, 0, zbytes, stream);

    const __hip_bfloat16* Wg1b  = Wc + 0 * 16384;
    const __hip_bfloat16* Wg2b  = Wc + 1 * 16384;
    const __hip_bfloat16* Wqkvs = Wc + 2 * 16384;   // q,k,v,skip contiguous
    k_cvt6<<<384, 256, 0, stream>>>(W_g1, W_g2, Wq, Wk, Wv, Wskip, Wc);

    int gE = (E + 255) / 256;
    k_count<<<gE, 256, 0, stream>>>(ei, indeg, E);
    k_scan<<<1, 1024, 0, stream>>>(indeg, off, dinv, N);
    k_fill<<<gE, 256, 0, stream>>>(ei, off, cursor, col, E);

    int gN = (N + 3) / 4;       // gather kernels: 4 waves/block, 1 node/wave
    int gM = (N + 63) / 64;     // MFMA kernels: 64 rows/block

    k_linear<32, true, true, __hip_bfloat16><<<2048, 256, 0, stream>>>(nf, W_emb, b_emb, X0b, N);   // x0 bf16
    k_lin_mfma_scale<<<gM, 256, 0, stream>>>(X0b, Wg1b, dinv, XWb, N);                              // xw1' = xw1*dinv
    k_gcn_agg<<<gN, 256, 0, stream>>>((const uint*)XWb, off, col, dinv, b_g1, (uint2*)X1b, N);      // x1
    k_lin_mfma_scale<<<gM, 256, 0, stream>>>(X1b, Wg2b, dinv, XWb, N);                              // xw2'
    k_gcn_agg<<<gN, 256, 0, stream>>>((const uint*)XWb, off, col, dinv, b_g2, (uint2*)X0b, N);      // x2

    k_qkvs_mfma<<<gM, 256, 0, stream>>>(X0b, Wqkvs, bq, bk, bv, bskip, Cqb, KV, Bb, N);             // q,KV,skip
    k_attn<<<gN, 256, 0, stream>>>((const uint*)Cqb, (const uint2*)KV, off, col, (uint*)Bb, N);     // Bb += attn

    k_pool<<<gM, 128, 0, stream>>>(Bb, batch, gsum, cnt, N);

    float* out_qv = (float*)d_out;
    float* out_h  = out_qv + (size_t)B * 14;
    float* out_c  = out_h + (size_t)B * 128;
    k_final<<<B, 128, 0, stream>>>(gsum, cnt, w, Wgam, bgam, Wbet, bbet, hprev, cprev,
                                   Wih, bih, Whh, bhh, lng, lnb,
                                   Wa1, ba1, Wa2, ba2, Wv1, bv1, Wv2, bv2,
                                   out_qv, out_h, out_c);
}

// Round 8
// 566.045 us; speedup vs baseline: 1.1886x; 1.1886x over previous
//
#include <hip/hip_runtime.h>
#include <hip/hip_bf16.h>
#include <math.h>

typedef unsigned int uint;
typedef __bf16 bf16_t;
typedef bf16_t bf16x8 __attribute__((ext_vector_type(8)));
typedef float f32x4 __attribute__((ext_vector_type(4)));

__device__ inline float2 bf2_unpack(uint u) {
    union { uint i; float f; } a, b;
    a.i = u << 16;
    b.i = u & 0xffff0000u;
    return make_float2(a.f, b.f);   // (lo, hi)
}

__device__ inline uint bf2_pack(float lo, float hi) {
    __hip_bfloat162 h;
    h.x = __float2bfloat16(lo);
    h.y = __float2bfloat16(hi);
    return *(uint*)&h;              // hi<<16 | lo
}

__device__ inline void store_out(float* p, float v) { *p = v; }
__device__ inline void store_out(__hip_bfloat16* p, float v) { *p = __float2bfloat16(v); }

// ---------------- CSR build ----------------
__global__ __launch_bounds__(256) void k_count(const int* __restrict__ ei, int* __restrict__ indeg, int E) {
    int e = blockIdx.x * 256 + threadIdx.x;
    if (e < E) atomicAdd(&indeg[ei[E + e]], 1);
}

// per-1024-chunk sums (coalesced int4)
__global__ __launch_bounds__(256) void k_bsum(const int* __restrict__ indeg, int* __restrict__ bsum, int n) {
    __shared__ int sd[256];
    int t = threadIdx.x;
    int base = blockIdx.x * 1024 + t * 4;
    int s = 0;
    if (base + 3 < n) {
        int4 v = *(const int4*)(indeg + base);
        s = v.x + v.y + v.z + v.w;
    } else {
        for (int j = 0; j < 4; ++j) if (base + j < n) s += indeg[base + j];
    }
    sd[t] = s;
    __syncthreads();
    for (int d = 128; d > 0; d >>= 1) { if (t < d) sd[t] += sd[t + d]; __syncthreads(); }
    if (t == 0) bsum[blockIdx.x] = sd[0];
}

// one small block: exclusive scan of block sums; also sets off[n]=E
__global__ __launch_bounds__(256) void k_scanb(const int* __restrict__ bsum, int* __restrict__ bexcl,
                                               int* __restrict__ off, int n, int nb, int E) {
    __shared__ int sd[256];
    int t = threadIdx.x;
    int v = (t < nb) ? bsum[t] : 0;
    sd[t] = v;
    __syncthreads();
    for (int d = 1; d < 256; d <<= 1) {
        int a = (t >= d) ? sd[t - d] : 0;
        __syncthreads();
        sd[t] += a;
        __syncthreads();
    }
    if (t < nb) bexcl[t] = sd[t] - v;
    if (t == 0) off[n] = E;
}

// per-chunk local exclusive scan + scatter off/dinv (coalesced)
__global__ __launch_bounds__(256) void k_scatter(const int* __restrict__ indeg, const int* __restrict__ bexcl,
                                                 int* __restrict__ off, float* __restrict__ dinv, int n) {
    __shared__ int sd[256];
    int t = threadIdx.x;
    int base = blockIdx.x * 1024 + t * 4;
    int4 v = {0, 0, 0, 0};
    bool full = (base + 3 < n);
    if (full) v = *(const int4*)(indeg + base);
    else { for (int j = 0; j < 4; ++j) if (base + j < n) ((int*)&v)[j] = indeg[base + j]; }
    int s = v.x + v.y + v.z + v.w;
    sd[t] = s;
    __syncthreads();
    for (int d = 1; d < 256; d <<= 1) {
        int a = (t >= d) ? sd[t - d] : 0;
        __syncthreads();
        sd[t] += a;
        __syncthreads();
    }
    int run = bexcl[blockIdx.x] + sd[t] - s;
    int4 o;
    o.x = run; run += v.x;
    o.y = run; run += v.y;
    o.z = run; run += v.z;
    o.w = run;
    float4 dv;
    dv.x = rsqrtf((float)(v.x + 1));
    dv.y = rsqrtf((float)(v.y + 1));
    dv.z = rsqrtf((float)(v.z + 1));
    dv.w = rsqrtf((float)(v.w + 1));
    if (full) {
        *(int4*)(off + base) = o;
        *(float4*)(dinv + base) = dv;
    } else {
        for (int j = 0; j < 4; ++j) if (base + j < n) { off[base + j] = ((int*)&o)[j]; dinv[base + j] = ((float*)&dv)[j]; }
    }
}

__global__ __launch_bounds__(256) void k_fill(const int* __restrict__ ei, const int* __restrict__ off,
                                              int* __restrict__ cursor, int* __restrict__ col, int E) {
    int e = blockIdx.x * 256 + threadIdx.x;
    if (e < E) {
        int d = ei[E + e];
        int p = atomicAdd(&cursor[d], 1);
        col[off[d] + p] = ei[e];
    }
}

// ---------------- fp32 -> bf16 weight conversion (6 x 128x128 mats) ----------------
__global__ __launch_bounds__(256) void k_cvt6(const float* __restrict__ s0, const float* __restrict__ s1,
                                              const float* __restrict__ s2, const float* __restrict__ s3,
                                              const float* __restrict__ s4, const float* __restrict__ s5,
                                              __hip_bfloat16* __restrict__ dst) {
    int i = blockIdx.x * 256 + threadIdx.x;
    if (i >= 6 * 16384) return;
    int m = i >> 14;
    const float* s = (m == 0) ? s0 : (m == 1) ? s1 : (m == 2) ? s2 : (m == 3) ? s3 : (m == 4) ? s4 : s5;
    dst[i] = __float2bfloat16(s[i & 16383]);
}

// ---------------- scalar linear for FI=32 (embed), bf16 out ----------------
template<int FI, bool BIAS, bool RELU, typename OUT>
__global__ __launch_bounds__(256) void k_linear(const float* __restrict__ x, const float* __restrict__ W,
                                                const float* __restrict__ b, OUT* __restrict__ y, int n) {
    __shared__ float4 Wt4[(FI / 4) * 128];
    __shared__ float4 xl[2][FI / 4];
    int t = threadIdx.x & 127;
    int h = threadIdx.x >> 7;
    {
        const float4* Wrow = (const float4*)(W + (size_t)t * FI);
        #pragma unroll
        for (int k4 = h * (FI / 8); k4 < (h + 1) * (FI / 8); ++k4) Wt4[k4 * 128 + t] = Wrow[k4];
    }
    float bias = 0.f;
    if (BIAS) bias = b[t];
    __syncthreads();
    for (int n0 = blockIdx.x * 2; n0 < n; n0 += gridDim.x * 2) {
        int nn = n0 + h;
        if (nn < n && t < FI / 4) xl[h][t] = ((const float4*)(x + (size_t)nn * FI))[t];
        __syncthreads();
        if (nn < n) {
            float acc = bias;
            #pragma unroll
            for (int k4 = 0; k4 < FI / 4; ++k4) {
                float4 xv = xl[h][k4];
                float4 wv = Wt4[k4 * 128 + t];
                acc += xv.x * wv.x + xv.y * wv.y + xv.z * wv.z + xv.w * wv.w;
            }
            if (RELU) acc = fmaxf(acc, 0.f);
            store_out(&y[(size_t)nn * 128 + t], acc);
        }
        __syncthreads();
    }
}

// ---------------- MFMA linear with per-row dinv prescale ----------------
__global__ __launch_bounds__(256) void k_lin_mfma_scale(const __hip_bfloat16* __restrict__ X,
                                                        const __hip_bfloat16* __restrict__ W,
                                                        const float* __restrict__ dinv,
                                                        __hip_bfloat16* __restrict__ y, int n) {
    int wave = threadIdx.x >> 6, lane = threadIdx.x & 63;
    int r0 = blockIdx.x * 64 + wave * 16;
    if (r0 >= n) return;
    int mrow = r0 + (lane & 15);
    if (mrow >= n) mrow = n - 1;
    int kk4 = lane >> 4;
    const bf16x8* xr = (const bf16x8*)((const bf16_t*)X + (size_t)mrow * 128);
    bf16x8 a0 = xr[0 * 4 + kk4];
    bf16x8 a1 = xr[1 * 4 + kk4];
    bf16x8 a2 = xr[2 * 4 + kk4];
    bf16x8 a3 = xr[3 * 4 + kk4];
    int orow = (lane >> 4) * 4;
    int ocol = lane & 15;
    float dv[4];
    #pragma unroll
    for (int j = 0; j < 4; ++j) {
        int row = r0 + orow + j;
        dv[j] = (row < n) ? dinv[row] : 0.f;
    }
    #pragma unroll
    for (int c = 0; c < 8; ++c) {
        const bf16x8* wr = (const bf16x8*)((const bf16_t*)W + (size_t)(c * 16 + (lane & 15)) * 128);
        bf16x8 b0 = wr[0 * 4 + kk4];
        bf16x8 b1 = wr[1 * 4 + kk4];
        bf16x8 b2 = wr[2 * 4 + kk4];
        bf16x8 b3 = wr[3 * 4 + kk4];
        f32x4 acc = {0.f, 0.f, 0.f, 0.f};
        acc = __builtin_amdgcn_mfma_f32_16x16x32_bf16(a0, b0, acc, 0, 0, 0);
        acc = __builtin_amdgcn_mfma_f32_16x16x32_bf16(a1, b1, acc, 0, 0, 0);
        acc = __builtin_amdgcn_mfma_f32_16x16x32_bf16(a2, b2, acc, 0, 0, 0);
        acc = __builtin_amdgcn_mfma_f32_16x16x32_bf16(a3, b3, acc, 0, 0, 0);
        int gcol = c * 16 + ocol;
        #pragma unroll
        for (int j = 0; j < 4; ++j) {
            int row = r0 + orow + j;
            if (row < n) store_out(&y[(size_t)row * 128 + gcol], acc[j] * dv[j]);
        }
    }
}

// ---------------- fused q/k/v/skip MFMA ----------------
// q -> Cqb bf16 (x0.25); k buffered in regs; v -> KVp uint per feature (hi=k, lo=v), coalesced 4B writes;
// skip -> Bb bf16.
__global__ __launch_bounds__(256) void k_qkvs_mfma(const __hip_bfloat16* __restrict__ X,
                                                   const __hip_bfloat16* __restrict__ W4,
                                                   const float* __restrict__ bq, const float* __restrict__ bk,
                                                   const float* __restrict__ bv, const float* __restrict__ bs,
                                                   __hip_bfloat16* __restrict__ Cqb, uint* __restrict__ KVp,
                                                   __hip_bfloat16* __restrict__ Bb, int n) {
    int wave = threadIdx.x >> 6, lane = threadIdx.x & 63;
    int r0 = blockIdx.x * 64 + wave * 16;
    if (r0 >= n) return;
    int mrow = r0 + (lane & 15);
    if (mrow >= n) mrow = n - 1;
    int kk4 = lane >> 4;
    const bf16x8* xr = (const bf16x8*)((const bf16_t*)X + (size_t)mrow * 128);
    bf16x8 a0 = xr[0 * 4 + kk4];
    bf16x8 a1 = xr[1 * 4 + kk4];
    bf16x8 a2 = xr[2 * 4 + kk4];
    bf16x8 a3 = xr[3 * 4 + kk4];
    int orow = (lane >> 4) * 4;
    int ocol = lane & 15;
    float karr[32];
    #pragma unroll
    for (int m = 0; m < 4; ++m) {
        const bf16_t* Wm = (const bf16_t*)W4 + (size_t)m * 16384;
        const float* bias = (m == 0) ? bq : (m == 1) ? bk : (m == 2) ? bv : bs;
        #pragma unroll
        for (int c = 0; c < 8; ++c) {
            const bf16x8* wr = (const bf16x8*)(Wm + (size_t)(c * 16 + (lane & 15)) * 128);
            bf16x8 b0 = wr[0 * 4 + kk4];
            bf16x8 b1 = wr[1 * 4 + kk4];
            bf16x8 b2 = wr[2 * 4 + kk4];
            bf16x8 b3 = wr[3 * 4 + kk4];
            f32x4 acc = {0.f, 0.f, 0.f, 0.f};
            acc = __builtin_amdgcn_mfma_f32_16x16x32_bf16(a0, b0, acc, 0, 0, 0);
            acc = __builtin_amdgcn_mfma_f32_16x16x32_bf16(a1, b1, acc, 0, 0, 0);
            acc = __builtin_amdgcn_mfma_f32_16x16x32_bf16(a2, b2, acc, 0, 0, 0);
            acc = __builtin_amdgcn_mfma_f32_16x16x32_bf16(a3, b3, acc, 0, 0, 0);
            int gcol = c * 16 + ocol;
            float bb = bias[gcol];
            #pragma unroll
            for (int j = 0; j < 4; ++j) {
                int row = r0 + orow + j;
                float v = acc[j] + bb;
                if (m == 1) karr[c * 4 + j] = v;
                if (row >= n) continue;
                if (m == 0) store_out(&Cqb[(size_t)row * 128 + gcol], v * 0.25f);
                else if (m == 2) KVp[(size_t)row * 128 + gcol] = bf2_pack(v, karr[c * 4 + j]);  // lo=v, hi=k
                else if (m == 3) store_out(&Bb[(size_t)row * 128 + gcol], v);
            }
        }
    }
}

// ---------------- GCN aggregation: 1 wave/node, prescaled adds, unroll 8 ----------------
__global__ __launch_bounds__(256) void k_gcn_agg(const uint* __restrict__ xw, const int* __restrict__ off,
                                                 const int* __restrict__ col, const float* __restrict__ dinv,
                                                 const float* __restrict__ bias, __hip_bfloat162* __restrict__ y, int n) {
    int wid = (blockIdx.x * 256 + threadIdx.x) >> 6;
    int lane = threadIdx.x & 63;
    if (wid >= n) return;
    float di = dinv[wid];
    float2 acc = bf2_unpack(xw[(size_t)wid * 64 + lane]);  // self (prescaled by its dinv)
    int i = off[wid], i1 = off[wid + 1];
    for (; i + 7 < i1; i += 8) {
        uint u0 = xw[(size_t)col[i] * 64 + lane];
        uint u1 = xw[(size_t)col[i + 1] * 64 + lane];
        uint u2 = xw[(size_t)col[i + 2] * 64 + lane];
        uint u3 = xw[(size_t)col[i + 3] * 64 + lane];
        uint u4 = xw[(size_t)col[i + 4] * 64 + lane];
        uint u5 = xw[(size_t)col[i + 5] * 64 + lane];
        uint u6 = xw[(size_t)col[i + 6] * 64 + lane];
        uint u7 = xw[(size_t)col[i + 7] * 64 + lane];
        float2 x0 = bf2_unpack(u0), x1 = bf2_unpack(u1), x2 = bf2_unpack(u2), x3 = bf2_unpack(u3);
        float2 x4 = bf2_unpack(u4), x5 = bf2_unpack(u5), x6 = bf2_unpack(u6), x7 = bf2_unpack(u7);
        acc.x += ((x0.x + x1.x) + (x2.x + x3.x)) + ((x4.x + x5.x) + (x6.x + x7.x));
        acc.y += ((x0.y + x1.y) + (x2.y + x3.y)) + ((x4.y + x5.y) + (x6.y + x7.y));
    }
    for (; i < i1; ++i) {
        float2 x0 = bf2_unpack(xw[(size_t)col[i] * 64 + lane]);
        acc.x += x0.x;
        acc.y += x0.y;
    }
    float2 b2 = ((const float2*)bias)[lane];
    __hip_bfloat162 o;
    o.x = __float2bfloat16(fmaxf(di * acc.x + b2.x, 0.f));
    o.y = __float2bfloat16(fmaxf(di * acc.y + b2.y, 0.f));
    y[(size_t)wid * 64 + lane] = o;
}

// ---------------- transformer attention: 1 wave/dst, packed KV (uint/feat: hi=k lo=v) ----------------
// q bf16 prescaled by 0.25. Lane l covers feats {2l,2l+1}: one uint2 load per edge.
// head h = l>>3 spans lanes 8h..8h+7.
__global__ __launch_bounds__(256) void k_attn(const uint* __restrict__ qb, const uint2* __restrict__ kv2,
                                              const int* __restrict__ off, const int* __restrict__ col,
                                              uint* __restrict__ io, int n) {
    int wid = (blockIdx.x * 256 + threadIdx.x) >> 6;
    int lane = threadIdx.x & 63;
    if (wid >= n) return;
    float2 q2 = bf2_unpack(qb[(size_t)wid * 64 + lane]);
    float m = -INFINITY, s = 0.f;
    float2 acc = make_float2(0.f, 0.f);
    int i = off[wid], i1 = off[wid + 1];
    for (; i + 7 < i1; i += 8) {
        uint2 u0 = kv2[((size_t)col[i] << 6) + lane];
        uint2 u1 = kv2[((size_t)col[i + 1] << 6) + lane];
        uint2 u2 = kv2[((size_t)col[i + 2] << 6) + lane];
        uint2 u3 = kv2[((size_t)col[i + 3] << 6) + lane];
        uint2 u4 = kv2[((size_t)col[i + 4] << 6) + lane];
        uint2 u5 = kv2[((size_t)col[i + 5] << 6) + lane];
        uint2 u6 = kv2[((size_t)col[i + 6] << 6) + lane];
        uint2 u7 = kv2[((size_t)col[i + 7] << 6) + lane];
        // unpack: (.x -> feat 2l: lo=v,hi=k) (.y -> feat 2l+1)
        float2 a0 = bf2_unpack(u0.x), b0 = bf2_unpack(u0.y);
        float2 a1 = bf2_unpack(u1.x), b1 = bf2_unpack(u1.y);
        float2 a2 = bf2_unpack(u2.x), b2 = bf2_unpack(u2.y);
        float2 a3 = bf2_unpack(u3.x), b3 = bf2_unpack(u3.y);
        float2 a4 = bf2_unpack(u4.x), b4 = bf2_unpack(u4.y);
        float2 a5 = bf2_unpack(u5.x), b5 = bf2_unpack(u5.y);
        float2 a6 = bf2_unpack(u6.x), b6 = bf2_unpack(u6.y);
        float2 a7 = bf2_unpack(u7.x), b7 = bf2_unpack(u7.y);
        float l0 = q2.x * a0.y + q2.y * b0.y;
        float l1 = q2.x * a1.y + q2.y * b1.y;
        float l2 = q2.x * a2.y + q2.y * b2.y;
        float l3 = q2.x * a3.y + q2.y * b3.y;
        float l4 = q2.x * a4.y + q2.y * b4.y;
        float l5 = q2.x * a5.y + q2.y * b5.y;
        float l6 = q2.x * a6.y + q2.y * b6.y;
        float l7 = q2.x * a7.y + q2.y * b7.y;
        l0 += __shfl_xor(l0, 1); l1 += __shfl_xor(l1, 1); l2 += __shfl_xor(l2, 1); l3 += __shfl_xor(l3, 1);
        l4 += __shfl_xor(l4, 1); l5 += __shfl_xor(l5, 1); l6 += __shfl_xor(l6, 1); l7 += __shfl_xor(l7, 1);
        l0 += __shfl_xor(l0, 2); l1 += __shfl_xor(l1, 2); l2 += __shfl_xor(l2, 2); l3 += __shfl_xor(l3, 2);
        l4 += __shfl_xor(l4, 2); l5 += __shfl_xor(l5, 2); l6 += __shfl_xor(l6, 2); l7 += __shfl_xor(l7, 2);
        l0 += __shfl_xor(l0, 4); l1 += __shfl_xor(l1, 4); l2 += __shfl_xor(l2, 4); l3 += __shfl_xor(l3, 4);
        l4 += __shfl_xor(l4, 4); l5 += __shfl_xor(l5, 4); l6 += __shfl_xor(l6, 4); l7 += __shfl_xor(l7, 4);
        float mx = fmaxf(fmaxf(fmaxf(l0, l1), fmaxf(l2, l3)), fmaxf(fmaxf(l4, l5), fmaxf(l6, l7)));
        if (mx > m) {                         // rescale once per 8-edge chunk
            float corr = __expf(m - mx);      // 0 on first chunk (m=-inf)
            s *= corr;
            acc.x *= corr;
            acc.y *= corr;
            m = mx;
        }
        float e0 = __expf(l0 - m), e1 = __expf(l1 - m), e2 = __expf(l2 - m), e3 = __expf(l3 - m);
        float e4 = __expf(l4 - m), e5 = __expf(l5 - m), e6 = __expf(l6 - m), e7 = __expf(l7 - m);
        s += ((e0 + e1) + (e2 + e3)) + ((e4 + e5) + (e6 + e7));
        acc.x += ((e0 * a0.x + e1 * a1.x) + (e2 * a2.x + e3 * a3.x)) + ((e4 * a4.x + e5 * a5.x) + (e6 * a6.x + e7 * a7.x));
        acc.y += ((e0 * b0.x + e1 * b1.x) + (e2 * b2.x + e3 * b3.x)) + ((e4 * b4.x + e5 * b5.x) + (e6 * b6.x + e7 * b7.x));
    }
    for (; i < i1; ++i) {
        uint2 u0 = kv2[((size_t)col[i] << 6) + lane];
        float2 a0 = bf2_unpack(u0.x), b0 = bf2_unpack(u0.y);
        float l0 = q2.x * a0.y + q2.y * b0.y;
        l0 += __shfl_xor(l0, 1);
        l0 += __shfl_xor(l0, 2);
        l0 += __shfl_xor(l0, 4);
        if (l0 > m) {
            float corr = __expf(m - l0);
            s *= corr;
            acc.x *= corr;
            acc.y *= corr;
            m = l0;
        }
        float e0 = __expf(l0 - m);
        s += e0;
        acc.x += e0 * a0.x;
        acc.y += e0 * b0.x;
    }
    float inv = 1.f / fmaxf(s, 1e-16f);
    uint* orow = io + (size_t)wid * 64 + lane;
    float2 o2 = bf2_unpack(*orow);               // skip connection already there
    o2.x += acc.x * inv;
    o2.y += acc.y * inv;
    *orow = bf2_pack(o2.x, o2.y);
}

// ---------------- mean-pool per graph (batch sorted), bf16 in, 64 nodes/block ----------------
__global__ __launch_bounds__(128) void k_pool(const __hip_bfloat16* __restrict__ x, const int* __restrict__ batch,
                                              float* __restrict__ gsum, float* __restrict__ cnt, int n) {
    int t = threadIdx.x;
    int start = blockIdx.x * 64;
    int end = start + 64; if (end > n) end = n;
    if (start >= n) return;
    int cur = batch[start];
    float acc = 0.f;
    int run = 0;
    for (int nn = start; nn < end; ++nn) {
        int g = batch[nn];
        if (g != cur) {
            atomicAdd(&gsum[cur * 128 + t], acc);
            if (t == 0) atomicAdd(&cnt[cur], (float)run);
            acc = 0.f; run = 0; cur = g;
        }
        acc += __bfloat162float(x[(size_t)nn * 128 + t]);
        run++;
    }
    atomicAdd(&gsum[cur * 128 + t], acc);
    if (t == 0) atomicAdd(&cnt[cur], (float)run);
}

// ---------------- FiLM + LSTM + LayerNorm + dueling heads, one block per graph ----------------
__global__ __launch_bounds__(128) void k_final(
    const float* __restrict__ gsum, const float* __restrict__ cnt, const float* __restrict__ w,
    const float* __restrict__ Wgam, const float* __restrict__ bgam,
    const float* __restrict__ Wbet, const float* __restrict__ bbet,
    const float* __restrict__ hprev, const float* __restrict__ cprev,
    const float* __restrict__ Wih, const float* __restrict__ bih,
    const float* __restrict__ Whh, const float* __restrict__ bhh,
    const float* __restrict__ lng, const float* __restrict__ lnb,
    const float* __restrict__ Wa1, const float* __restrict__ ba1,
    const float* __restrict__ Wa2, const float* __restrict__ ba2,
    const float* __restrict__ Wv1, const float* __restrict__ bv1,
    const float* __restrict__ Wv2, const float* __restrict__ bv2,
    float* __restrict__ out_qv, float* __restrict__ out_h, float* __restrict__ out_c) {
    int g = blockIdx.x, t = threadIdx.x;
    __shared__ __align__(16) float ge[128], hp[128], hn[128], r1[128], a1s[128], red[128];
    __shared__ float adv[16], val[2], mu_s, var_s;

    float w0 = w[g * 2 + 0], w1 = w[g * 2 + 1];
    float c = fmaxf(cnt[g], 1.f);
    float mn = gsum[g * 128 + t] / c;
    float gam = w0 * Wgam[2 * t] + w1 * Wgam[2 * t + 1] + bgam[t];
    float bet = w0 * Wbet[2 * t] + w1 * Wbet[2 * t + 1] + bbet[t];
    ge[t] = (1.f + gam) * mn + bet;
    hp[t] = hprev[g * 128 + t];
    __syncthreads();

    float gi = bih[t] + bhh[t];
    float gf = bih[128 + t] + bhh[128 + t];
    float gg = bih[256 + t] + bhh[256 + t];
    float go = bih[384 + t] + bhh[384 + t];
    {
        const float4* ge4 = (const float4*)ge;
        const float4* hp4 = (const float4*)hp;
        const float4* Ai = (const float4*)(Wih + (size_t)t * 128);
        const float4* Af = (const float4*)(Wih + (size_t)(128 + t) * 128);
        const float4* Ag = (const float4*)(Wih + (size_t)(256 + t) * 128);
        const float4* Ao = (const float4*)(Wih + (size_t)(384 + t) * 128);
        const float4* Hi = (const float4*)(Whh + (size_t)t * 128);
        const float4* Hf = (const float4*)(Whh + (size_t)(128 + t) * 128);
        const float4* Hg = (const float4*)(Whh + (size_t)(256 + t) * 128);
        const float4* Ho = (const float4*)(Whh + (size_t)(384 + t) * 128);
        #pragma unroll 4
        for (int k4 = 0; k4 < 32; ++k4) {
            float4 a = ge4[k4], h4 = hp4[k4], u;
            u = Ai[k4]; gi += a.x * u.x + a.y * u.y + a.z * u.z + a.w * u.w;
            u = Hi[k4]; gi += h4.x * u.x + h4.y * u.y + h4.z * u.z + h4.w * u.w;
            u = Af[k4]; gf += a.x * u.x + a.y * u.y + a.z * u.z + a.w * u.w;
            u = Hf[k4]; gf += h4.x * u.x + h4.y * u.y + h4.z * u.z + h4.w * u.w;
            u = Ag[k4]; gg += a.x * u.x + a.y * u.y + a.z * u.z + a.w * u.w;
            u = Hg[k4]; gg += h4.x * u.x + h4.y * u.y + h4.z * u.z + h4.w * u.w;
            u = Ao[k4]; go += a.x * u.x + a.y * u.y + a.z * u.z + a.w * u.w;
            u = Ho[k4]; go += h4.x * u.x + h4.y * u.y + h4.z * u.z + h4.w * u.w;
        }
    }
    float ig = 1.f / (1.f + __expf(-gi));
    float fg = 1.f / (1.f + __expf(-gf));
    float gc = tanhf(gg);
    float og = 1.f / (1.f + __expf(-go));
    float craw = fg * cprev[g * 128 + t] + ig * gc;
    float hraw = og * tanhf(craw);
    out_c[g * 128 + t] = fminf(fmaxf(craw, -1e6f), 1e6f);

    red[t] = hraw;
    __syncthreads();
    for (int s2 = 64; s2 > 0; s2 >>= 1) { if (t < s2) red[t] += red[t + s2]; __syncthreads(); }
    if (t == 0) mu_s = red[0] * (1.f / 128.f);
    __syncthreads();
    float mu = mu_s;
    float d = hraw - mu;
    red[t] = d * d;
    __syncthreads();
    for (int s2 = 64; s2 > 0; s2 >>= 1) { if (t < s2) red[t] += red[t + s2]; __syncthreads(); }
    if (t == 0) var_s = red[0] * (1.f / 128.f);
    __syncthreads();
    float hv = d * rsqrtf(var_s + 1e-5f) * lng[t] + lnb[t];
    hn[t] = hv;
    out_h[g * 128 + t] = hv;
    __syncthreads();

    float accv = bv1[t], acca = ba1[t];
    {
        const float4* hn4 = (const float4*)hn;
        const float4* V1 = (const float4*)(Wv1 + (size_t)t * 128);
        const float4* A1 = (const float4*)(Wa1 + (size_t)t * 128);
        #pragma unroll 4
        for (int k4 = 0; k4 < 32; ++k4) {
            float4 hh = hn4[k4], u;
            u = V1[k4]; accv += hh.x * u.x + hh.y * u.y + hh.z * u.z + hh.w * u.w;
            u = A1[k4]; acca += hh.x * u.x + hh.y * u.y + hh.z * u.z + hh.w * u.w;
        }
    }
    r1[t] = fmaxf(accv, 0.f);
    a1s[t] = fmaxf(acca, 0.f);
    __syncthreads();
    if (t < 2) {
        float s = bv2[t];
        const float4* V2 = (const float4*)(Wv2 + (size_t)t * 128);
        const float4* r4 = (const float4*)r1;
        for (int k4 = 0; k4 < 32; ++k4) { float4 u = V2[k4], rr = r4[k4]; s += rr.x * u.x + rr.y * u.y + rr.z * u.z + rr.w * u.w; }
        val[t] = s;
    }
    if (t < 14) {
        float s = ba2[t];
        const float4* A2 = (const float4*)(Wa2 + (size_t)t * 128);
        const float4* a4 = (const float4*)a1s;
        for (int k4 = 0; k4 < 32; ++k4) { float4 u = A2[k4], aa = a4[k4]; s += aa.x * u.x + aa.y * u.y + aa.z * u.z + aa.w * u.w; }
        adv[t] = s;
    }
    __syncthreads();
    if (t < 14) {
        int o = t & 1;
        float mo = (adv[o] + adv[o + 2] + adv[o + 4] + adv[o + 6] + adv[o + 8] + adv[o + 10] + adv[o + 12]) * (1.f / 7.f);
        float qq = val[o] + adv[t] - mo;
        if (isnan(qq)) qq = 0.f;
        qq = fminf(fmaxf(qq, -100.f), 100.f);
        out_qv[g * 14 + t] = qq;
    }
}

extern "C" void kernel_launch(void* const* d_in, const int* in_sizes, int n_in,
                              void* d_out, int out_size, void* d_ws, size_t ws_size,
                              hipStream_t stream) {
    const float* nf    = (const float*)d_in[0];
    const int*   ei    = (const int*)d_in[1];
    const int*   batch = (const int*)d_in[2];
    const float* w     = (const float*)d_in[3];
    const float* hprev = (const float*)d_in[4];
    const float* cprev = (const float*)d_in[5];
    const float* W_emb = (const float*)d_in[6];  const float* b_emb = (const float*)d_in[7];
    const float* W_g1  = (const float*)d_in[8];  const float* b_g1  = (const float*)d_in[9];
    const float* W_g2  = (const float*)d_in[10]; const float* b_g2  = (const float*)d_in[11];
    const float* Wq    = (const float*)d_in[12]; const float* bq    = (const float*)d_in[13];
    const float* Wk    = (const float*)d_in[14]; const float* bk    = (const float*)d_in[15];
    const float* Wv    = (const float*)d_in[16]; const float* bv    = (const float*)d_in[17];
    const float* Wskip = (const float*)d_in[18]; const float* bskip = (const float*)d_in[19];
    const float* Wgam  = (const float*)d_in[20]; const float* bgam  = (const float*)d_in[21];
    const float* Wbet  = (const float*)d_in[22]; const float* bbet  = (const float*)d_in[23];
    const float* Wih   = (const float*)d_in[24]; const float* bih   = (const float*)d_in[25];
    const float* Whh   = (const float*)d_in[26]; const float* bhh   = (const float*)d_in[27];
    const float* lng   = (const float*)d_in[28]; const float* lnb   = (const float*)d_in[29];
    const float* Wa1   = (const float*)d_in[30]; const float* ba1   = (const float*)d_in[31];
    const float* Wa2   = (const float*)d_in[32]; const float* ba2   = (const float*)d_in[33];
    const float* Wv1   = (const float*)d_in[34]; const float* bv1   = (const float*)d_in[35];
    const float* Wv2   = (const float*)d_in[36]; const float* bv2   = (const float*)d_in[37];

    int N = in_sizes[2];
    int E = in_sizes[1] / 2;
    int B = in_sizes[4] / 128;
    int nb = (N + 1023) / 1024;

    char* p = (char*)d_ws;
    auto alloc = [&](size_t bytes) { char* r = p; p += (bytes + 511) & ~(size_t)511; return r; };
    int*   indeg  = (int*)alloc((size_t)N * 4);
    int*   cursor = (int*)alloc((size_t)N * 4);
    float* gsum   = (float*)alloc((size_t)B * 128 * 4);
    float* cnt    = (float*)alloc((size_t)B * 4);
    size_t zbytes = (size_t)(p - (char*)d_ws);   // region zeroed each call
    int*   off    = (int*)alloc((size_t)(N + 1) * 4);
    int*   col    = (int*)alloc((size_t)E * 4);
    float* dinv   = (float*)alloc((size_t)N * 4);
    int*   bsum   = (int*)alloc((size_t)(nb + 1) * 4);
    int*   bexcl  = (int*)alloc((size_t)(nb + 1) * 4);
    __hip_bfloat16* Wc  = (__hip_bfloat16*)alloc((size_t)6 * 16384 * 2);  // bf16 weights: g1,g2,q,k,v,skip
    __hip_bfloat16* X0b = (__hip_bfloat16*)alloc((size_t)N * 128 * 2);    // x0 / x2
    __hip_bfloat16* X1b = (__hip_bfloat16*)alloc((size_t)N * 128 * 2);    // x1
    __hip_bfloat16* XWb = (__hip_bfloat16*)alloc((size_t)N * 128 * 2);    // xw scratch (prescaled)
    uint*  KV  = (uint*)alloc((size_t)N * 128 * 4);                       // packed k|v per feature
    __hip_bfloat16* Cqb = (__hip_bfloat16*)alloc((size_t)N * 128 * 2);    // q bf16 (x0.25)
    __hip_bfloat16* Bb  = (__hip_bfloat16*)alloc((size_t)N * 128 * 2);    // skip + attn out, bf16
    if ((size_t)(p - (char*)d_ws) > ws_size) return;

    hipMemsetAsync(d_ws, 0, zbytes, stream);

    const __hip_bfloat16* Wg1b  = Wc + 0 * 16384;
    const __hip_bfloat16* Wg2b  = Wc + 1 * 16384;
    const __hip_bfloat16* Wqkvs = Wc + 2 * 16384;   // q,k,v,skip contiguous
    k_cvt6<<<384, 256, 0, stream>>>(W_g1, W_g2, Wq, Wk, Wv, Wskip, Wc);

    int gE = (E + 255) / 256;
    k_count<<<gE, 256, 0, stream>>>(ei, indeg, E);
    k_bsum<<<nb, 256, 0, stream>>>(indeg, bsum, N);
    k_scanb<<<1, 256, 0, stream>>>(bsum, bexcl, off, N, nb, E);
    k_scatter<<<nb, 256, 0, stream>>>(indeg, bexcl, off, dinv, N);
    k_fill<<<gE, 256, 0, stream>>>(ei, off, cursor, col, E);

    int gN = (N + 3) / 4;       // gather kernels: 4 waves/block, 1 node/wave
    int gM = (N + 63) / 64;     // MFMA kernels: 64 rows/block

    k_linear<32, true, true, __hip_bfloat16><<<2048, 256, 0, stream>>>(nf, W_emb, b_emb, X0b, N);   // x0 bf16
    k_lin_mfma_scale<<<gM, 256, 0, stream>>>(X0b, Wg1b, dinv, XWb, N);                              // xw1' = xw1*dinv
    k_gcn_agg<<<gN, 256, 0, stream>>>((const uint*)XWb, off, col, dinv, b_g1, (__hip_bfloat162*)X1b, N); // x1
    k_lin_mfma_scale<<<gM, 256, 0, stream>>>(X1b, Wg2b, dinv, XWb, N);                              // xw2'
    k_gcn_agg<<<gN, 256, 0, stream>>>((const uint*)XWb, off, col, dinv, b_g2, (__hip_bfloat162*)X0b, N); // x2

    k_qkvs_mfma<<<gM, 256, 0, stream>>>(X0b, Wqkvs, bq, bk, bv, bskip, Cqb, KV, Bb, N);             // q,KV,skip
    k_attn<<<gN, 256, 0, stream>>>((const uint*)Cqb, (const uint2*)KV, off, col, (uint*)Bb, N);     // Bb += attn

    k_pool<<<gM, 128, 0, stream>>>(Bb, batch, gsum, cnt, N);

    float* out_qv = (float*)d_out;
    float* out_h  = out_qv + (size_t)B * 14;
    float* out_c  = out_h + (size_t)B * 128;
    k_final<<<B, 128, 0, stream>>>(gsum, cnt, w, Wgam, bgam, Wbet, bbet, hprev, cprev,
                                   Wih, bih, Whh, bhh, lng, lnb,
                                   Wa1, ba1, Wa2, ba2, Wv1, bv1, Wv2, bv2,
                                   out_qv, out_h, out_c);
}

// Round 9
// 554.068 us; speedup vs baseline: 1.2143x; 1.0216x over previous
//
#include <hip/hip_runtime.h>
#include <hip/hip_bf16.h>
#include <math.h>

typedef unsigned int uint;
typedef __bf16 bf16_t;
typedef bf16_t bf16x8 __attribute__((ext_vector_type(8)));
typedef float f32x4 __attribute__((ext_vector_type(4)));

__device__ inline float2 bf2_unpack(uint u) {
    union { uint i; float f; } a, b;
    a.i = u << 16;
    b.i = u & 0xffff0000u;
    return make_float2(a.f, b.f);   // (lo, hi)
}

__device__ inline uint bf2_pack(float lo, float hi) {
    __hip_bfloat162 h;
    h.x = __float2bfloat16(lo);
    h.y = __float2bfloat16(hi);
    return *(uint*)&h;              // hi<<16 | lo
}

__device__ inline void store_out(float* p, float v) { *p = v; }
__device__ inline void store_out(__hip_bfloat16* p, float v) { *p = __float2bfloat16(v); }

#define RFL(x) __builtin_amdgcn_readfirstlane(x)

// ---------------- CSR build ----------------
__global__ __launch_bounds__(256) void k_count(const int* __restrict__ ei, int* __restrict__ indeg, int E) {
    int e = blockIdx.x * 256 + threadIdx.x;
    if (e < E) atomicAdd(&indeg[ei[E + e]], 1);
}

// per-1024-chunk sums (coalesced int4)
__global__ __launch_bounds__(256) void k_bsum(const int* __restrict__ indeg, int* __restrict__ bsum, int n) {
    __shared__ int sd[256];
    int t = threadIdx.x;
    int base = blockIdx.x * 1024 + t * 4;
    int s = 0;
    if (base + 3 < n) {
        int4 v = *(const int4*)(indeg + base);
        s = v.x + v.y + v.z + v.w;
    } else {
        for (int j = 0; j < 4; ++j) if (base + j < n) s += indeg[base + j];
    }
    sd[t] = s;
    __syncthreads();
    for (int d = 128; d > 0; d >>= 1) { if (t < d) sd[t] += sd[t + d]; __syncthreads(); }
    if (t == 0) bsum[blockIdx.x] = sd[0];
}

// one small block: exclusive scan of block sums; also sets off[n]=E
__global__ __launch_bounds__(256) void k_scanb(const int* __restrict__ bsum, int* __restrict__ bexcl,
                                               int* __restrict__ off, int n, int nb, int E) {
    __shared__ int sd[256];
    int t = threadIdx.x;
    int v = (t < nb) ? bsum[t] : 0;
    sd[t] = v;
    __syncthreads();
    for (int d = 1; d < 256; d <<= 1) {
        int a = (t >= d) ? sd[t - d] : 0;
        __syncthreads();
        sd[t] += a;
        __syncthreads();
    }
    if (t < nb) bexcl[t] = sd[t] - v;
    if (t == 0) off[n] = E;
}

// per-chunk local exclusive scan + scatter off/dinv (coalesced)
__global__ __launch_bounds__(256) void k_scatter(const int* __restrict__ indeg, const int* __restrict__ bexcl,
                                                 int* __restrict__ off, float* __restrict__ dinv, int n) {
    __shared__ int sd[256];
    int t = threadIdx.x;
    int base = blockIdx.x * 1024 + t * 4;
    int4 v = {0, 0, 0, 0};
    bool full = (base + 3 < n);
    if (full) v = *(const int4*)(indeg + base);
    else { for (int j = 0; j < 4; ++j) if (base + j < n) ((int*)&v)[j] = indeg[base + j]; }
    int s = v.x + v.y + v.z + v.w;
    sd[t] = s;
    __syncthreads();
    for (int d = 1; d < 256; d <<= 1) {
        int a = (t >= d) ? sd[t - d] : 0;
        __syncthreads();
        sd[t] += a;
        __syncthreads();
    }
    int run = bexcl[blockIdx.x] + sd[t] - s;
    int4 o;
    o.x = run; run += v.x;
    o.y = run; run += v.y;
    o.z = run; run += v.z;
    o.w = run;
    float4 dv;
    dv.x = rsqrtf((float)(v.x + 1));
    dv.y = rsqrtf((float)(v.y + 1));
    dv.z = rsqrtf((float)(v.z + 1));
    dv.w = rsqrtf((float)(v.w + 1));
    if (full) {
        *(int4*)(off + base) = o;
        *(float4*)(dinv + base) = dv;
    } else {
        for (int j = 0; j < 4; ++j) if (base + j < n) { off[base + j] = ((int*)&o)[j]; dinv[base + j] = ((float*)&dv)[j]; }
    }
}

__global__ __launch_bounds__(256) void k_fill(const int* __restrict__ ei, const int* __restrict__ off,
                                              int* __restrict__ cursor, int* __restrict__ col, int E) {
    int e = blockIdx.x * 256 + threadIdx.x;
    if (e < E) {
        int d = ei[E + e];
        int p = atomicAdd(&cursor[d], 1);
        col[off[d] + p] = ei[e];
    }
}

// ---------------- fp32 -> bf16 weight conversion (6 x 128x128 mats) ----------------
__global__ __launch_bounds__(256) void k_cvt6(const float* __restrict__ s0, const float* __restrict__ s1,
                                              const float* __restrict__ s2, const float* __restrict__ s3,
                                              const float* __restrict__ s4, const float* __restrict__ s5,
                                              __hip_bfloat16* __restrict__ dst) {
    int i = blockIdx.x * 256 + threadIdx.x;
    if (i >= 6 * 16384) return;
    int m = i >> 14;
    const float* s = (m == 0) ? s0 : (m == 1) ? s1 : (m == 2) ? s2 : (m == 3) ? s3 : (m == 4) ? s4 : s5;
    dst[i] = __float2bfloat16(s[i & 16383]);
}

// ---------------- scalar linear for FI=32 (embed), bf16 out ----------------
template<int FI, bool BIAS, bool RELU, typename OUT>
__global__ __launch_bounds__(256) void k_linear(const float* __restrict__ x, const float* __restrict__ W,
                                                const float* __restrict__ b, OUT* __restrict__ y, int n) {
    __shared__ float4 Wt4[(FI / 4) * 128];
    __shared__ float4 xl[2][FI / 4];
    int t = threadIdx.x & 127;
    int h = threadIdx.x >> 7;
    {
        const float4* Wrow = (const float4*)(W + (size_t)t * FI);
        #pragma unroll
        for (int k4 = h * (FI / 8); k4 < (h + 1) * (FI / 8); ++k4) Wt4[k4 * 128 + t] = Wrow[k4];
    }
    float bias = 0.f;
    if (BIAS) bias = b[t];
    __syncthreads();
    for (int n0 = blockIdx.x * 2; n0 < n; n0 += gridDim.x * 2) {
        int nn = n0 + h;
        if (nn < n && t < FI / 4) xl[h][t] = ((const float4*)(x + (size_t)nn * FI))[t];
        __syncthreads();
        if (nn < n) {
            float acc = bias;
            #pragma unroll
            for (int k4 = 0; k4 < FI / 4; ++k4) {
                float4 xv = xl[h][k4];
                float4 wv = Wt4[k4 * 128 + t];
                acc += xv.x * wv.x + xv.y * wv.y + xv.z * wv.z + xv.w * wv.w;
            }
            if (RELU) acc = fmaxf(acc, 0.f);
            store_out(&y[(size_t)nn * 128 + t], acc);
        }
        __syncthreads();
    }
}

// ---------------- MFMA linear with per-row dinv prescale ----------------
__global__ __launch_bounds__(256) void k_lin_mfma_scale(const __hip_bfloat16* __restrict__ X,
                                                        const __hip_bfloat16* __restrict__ W,
                                                        const float* __restrict__ dinv,
                                                        __hip_bfloat16* __restrict__ y, int n) {
    int wave = threadIdx.x >> 6, lane = threadIdx.x & 63;
    int r0 = blockIdx.x * 64 + wave * 16;
    if (r0 >= n) return;
    int mrow = r0 + (lane & 15);
    if (mrow >= n) mrow = n - 1;
    int kk4 = lane >> 4;
    const bf16x8* xr = (const bf16x8*)((const bf16_t*)X + (size_t)mrow * 128);
    bf16x8 a0 = xr[0 * 4 + kk4];
    bf16x8 a1 = xr[1 * 4 + kk4];
    bf16x8 a2 = xr[2 * 4 + kk4];
    bf16x8 a3 = xr[3 * 4 + kk4];
    int orow = (lane >> 4) * 4;
    int ocol = lane & 15;
    float dv[4];
    #pragma unroll
    for (int j = 0; j < 4; ++j) {
        int row = r0 + orow + j;
        dv[j] = (row < n) ? dinv[row] : 0.f;
    }
    #pragma unroll
    for (int c = 0; c < 8; ++c) {
        const bf16x8* wr = (const bf16x8*)((const bf16_t*)W + (size_t)(c * 16 + (lane & 15)) * 128);
        bf16x8 b0 = wr[0 * 4 + kk4];
        bf16x8 b1 = wr[1 * 4 + kk4];
        bf16x8 b2 = wr[2 * 4 + kk4];
        bf16x8 b3 = wr[3 * 4 + kk4];
        f32x4 acc = {0.f, 0.f, 0.f, 0.f};
        acc = __builtin_amdgcn_mfma_f32_16x16x32_bf16(a0, b0, acc, 0, 0, 0);
        acc = __builtin_amdgcn_mfma_f32_16x16x32_bf16(a1, b1, acc, 0, 0, 0);
        acc = __builtin_amdgcn_mfma_f32_16x16x32_bf16(a2, b2, acc, 0, 0, 0);
        acc = __builtin_amdgcn_mfma_f32_16x16x32_bf16(a3, b3, acc, 0, 0, 0);
        int gcol = c * 16 + ocol;
        #pragma unroll
        for (int j = 0; j < 4; ++j) {
            int row = r0 + orow + j;
            if (row < n) store_out(&y[(size_t)row * 128 + gcol], acc[j] * dv[j]);
        }
    }
}

// ---------------- fused q/k/v/skip MFMA ----------------
// q -> Cqb bf16 (x0.25); k buffered in regs; v -> KVp uint per feature (hi=k, lo=v), coalesced 4B writes;
// skip -> Bb bf16.
__global__ __launch_bounds__(256) void k_qkvs_mfma(const __hip_bfloat16* __restrict__ X,
                                                   const __hip_bfloat16* __restrict__ W4,
                                                   const float* __restrict__ bq, const float* __restrict__ bk,
                                                   const float* __restrict__ bv, const float* __restrict__ bs,
                                                   __hip_bfloat16* __restrict__ Cqb, uint* __restrict__ KVp,
                                                   __hip_bfloat16* __restrict__ Bb, int n) {
    int wave = threadIdx.x >> 6, lane = threadIdx.x & 63;
    int r0 = blockIdx.x * 64 + wave * 16;
    if (r0 >= n) return;
    int mrow = r0 + (lane & 15);
    if (mrow >= n) mrow = n - 1;
    int kk4 = lane >> 4;
    const bf16x8* xr = (const bf16x8*)((const bf16_t*)X + (size_t)mrow * 128);
    bf16x8 a0 = xr[0 * 4 + kk4];
    bf16x8 a1 = xr[1 * 4 + kk4];
    bf16x8 a2 = xr[2 * 4 + kk4];
    bf16x8 a3 = xr[3 * 4 + kk4];
    int orow = (lane >> 4) * 4;
    int ocol = lane & 15;
    float karr[32];
    #pragma unroll
    for (int m = 0; m < 4; ++m) {
        const bf16_t* Wm = (const bf16_t*)W4 + (size_t)m * 16384;
        const float* bias = (m == 0) ? bq : (m == 1) ? bk : (m == 2) ? bv : bs;
        #pragma unroll
        for (int c = 0; c < 8; ++c) {
            const bf16x8* wr = (const bf16x8*)(Wm + (size_t)(c * 16 + (lane & 15)) * 128);
            bf16x8 b0 = wr[0 * 4 + kk4];
            bf16x8 b1 = wr[1 * 4 + kk4];
            bf16x8 b2 = wr[2 * 4 + kk4];
            bf16x8 b3 = wr[3 * 4 + kk4];
            f32x4 acc = {0.f, 0.f, 0.f, 0.f};
            acc = __builtin_amdgcn_mfma_f32_16x16x32_bf16(a0, b0, acc, 0, 0, 0);
            acc = __builtin_amdgcn_mfma_f32_16x16x32_bf16(a1, b1, acc, 0, 0, 0);
            acc = __builtin_amdgcn_mfma_f32_16x16x32_bf16(a2, b2, acc, 0, 0, 0);
            acc = __builtin_amdgcn_mfma_f32_16x16x32_bf16(a3, b3, acc, 0, 0, 0);
            int gcol = c * 16 + ocol;
            float bb = bias[gcol];
            #pragma unroll
            for (int j = 0; j < 4; ++j) {
                int row = r0 + orow + j;
                float v = acc[j] + bb;
                if (m == 1) karr[c * 4 + j] = v;
                if (row >= n) continue;
                if (m == 0) store_out(&Cqb[(size_t)row * 128 + gcol], v * 0.25f);
                else if (m == 2) KVp[(size_t)row * 128 + gcol] = bf2_pack(v, karr[c * 4 + j]);  // lo=v, hi=k
                else if (m == 3) store_out(&Bb[(size_t)row * 128 + gcol], v);
            }
        }
    }
}

// ---------------- GCN aggregation: 1 wave/node, scalar (SGPR) edge stream, unroll 8 ----------------
__global__ __launch_bounds__(256) void k_gcn_agg(const uint* __restrict__ xw, const int* __restrict__ off,
                                                 const int* __restrict__ col, const float* __restrict__ dinv,
                                                 const float* __restrict__ bias, __hip_bfloat162* __restrict__ y, int n) {
    int wid = RFL((int)((blockIdx.x * 256 + threadIdx.x) >> 6));   // wave-uniform -> SGPR
    int lane = threadIdx.x & 63;
    if (wid >= n) return;
    float di = dinv[wid];
    float2 acc = bf2_unpack(xw[(size_t)wid * 64 + lane]);  // self (prescaled by its dinv)
    int i = RFL(off[wid]), i1 = RFL(off[wid + 1]);
    for (; i + 7 < i1; i += 8) {
        int c0 = RFL(col[i]);
        int c1 = RFL(col[i + 1]);
        int c2 = RFL(col[i + 2]);
        int c3 = RFL(col[i + 3]);
        int c4 = RFL(col[i + 4]);
        int c5 = RFL(col[i + 5]);
        int c6 = RFL(col[i + 6]);
        int c7 = RFL(col[i + 7]);
        uint u0 = xw[(size_t)c0 * 64 + lane];
        uint u1 = xw[(size_t)c1 * 64 + lane];
        uint u2 = xw[(size_t)c2 * 64 + lane];
        uint u3 = xw[(size_t)c3 * 64 + lane];
        uint u4 = xw[(size_t)c4 * 64 + lane];
        uint u5 = xw[(size_t)c5 * 64 + lane];
        uint u6 = xw[(size_t)c6 * 64 + lane];
        uint u7 = xw[(size_t)c7 * 64 + lane];
        float2 x0 = bf2_unpack(u0), x1 = bf2_unpack(u1), x2 = bf2_unpack(u2), x3 = bf2_unpack(u3);
        float2 x4 = bf2_unpack(u4), x5 = bf2_unpack(u5), x6 = bf2_unpack(u6), x7 = bf2_unpack(u7);
        acc.x += ((x0.x + x1.x) + (x2.x + x3.x)) + ((x4.x + x5.x) + (x6.x + x7.x));
        acc.y += ((x0.y + x1.y) + (x2.y + x3.y)) + ((x4.y + x5.y) + (x6.y + x7.y));
    }
    for (; i < i1; ++i) {
        int c0 = RFL(col[i]);
        float2 x0 = bf2_unpack(xw[(size_t)c0 * 64 + lane]);
        acc.x += x0.x;
        acc.y += x0.y;
    }
    float2 b2 = ((const float2*)bias)[lane];
    __hip_bfloat162 o;
    o.x = __float2bfloat16(fmaxf(di * acc.x + b2.x, 0.f));
    o.y = __float2bfloat16(fmaxf(di * acc.y + b2.y, 0.f));
    y[(size_t)wid * 64 + lane] = o;
}

// ---------------- transformer attention: 1 wave/dst, packed KV, scalar edge stream ----------------
// q bf16 prescaled by 0.25. KV row = 64 uint2 (feat pair: lo=v, hi=k). Lane l covers feats {2l,2l+1}.
// head h = l>>3 spans lanes 8h..8h+7.
__global__ __launch_bounds__(256) void k_attn(const uint* __restrict__ qb, const uint2* __restrict__ kv2,
                                              const int* __restrict__ off, const int* __restrict__ col,
                                              uint* __restrict__ io, int n) {
    int wid = RFL((int)((blockIdx.x * 256 + threadIdx.x) >> 6));   // wave-uniform -> SGPR
    int lane = threadIdx.x & 63;
    if (wid >= n) return;
    float2 q2 = bf2_unpack(qb[(size_t)wid * 64 + lane]);
    float m = -INFINITY, s = 0.f;
    float2 acc = make_float2(0.f, 0.f);
    int i = RFL(off[wid]), i1 = RFL(off[wid + 1]);
    for (; i + 7 < i1; i += 8) {
        int c0 = RFL(col[i]);
        int c1 = RFL(col[i + 1]);
        int c2 = RFL(col[i + 2]);
        int c3 = RFL(col[i + 3]);
        int c4 = RFL(col[i + 4]);
        int c5 = RFL(col[i + 5]);
        int c6 = RFL(col[i + 6]);
        int c7 = RFL(col[i + 7]);
        uint2 u0 = kv2[((size_t)c0 << 6) + lane];
        uint2 u1 = kv2[((size_t)c1 << 6) + lane];
        uint2 u2 = kv2[((size_t)c2 << 6) + lane];
        uint2 u3 = kv2[((size_t)c3 << 6) + lane];
        uint2 u4 = kv2[((size_t)c4 << 6) + lane];
        uint2 u5 = kv2[((size_t)c5 << 6) + lane];
        uint2 u6 = kv2[((size_t)c6 << 6) + lane];
        uint2 u7 = kv2[((size_t)c7 << 6) + lane];
        // unpack: (.x -> feat 2l: lo=v,hi=k) (.y -> feat 2l+1)
        float2 a0 = bf2_unpack(u0.x), b0 = bf2_unpack(u0.y);
        float2 a1 = bf2_unpack(u1.x), b1 = bf2_unpack(u1.y);
        float2 a2 = bf2_unpack(u2.x), b2 = bf2_unpack(u2.y);
        float2 a3 = bf2_unpack(u3.x), b3 = bf2_unpack(u3.y);
        float2 a4 = bf2_unpack(u4.x), b4 = bf2_unpack(u4.y);
        float2 a5 = bf2_unpack(u5.x), b5 = bf2_unpack(u5.y);
        float2 a6 = bf2_unpack(u6.x), b6 = bf2_unpack(u6.y);
        float2 a7 = bf2_unpack(u7.x), b7 = bf2_unpack(u7.y);
        float l0 = q2.x * a0.y + q2.y * b0.y;
        float l1 = q2.x * a1.y + q2.y * b1.y;
        float l2 = q2.x * a2.y + q2.y * b2.y;
        float l3 = q2.x * a3.y + q2.y * b3.y;
        float l4 = q2.x * a4.y + q2.y * b4.y;
        float l5 = q2.x * a5.y + q2.y * b5.y;
        float l6 = q2.x * a6.y + q2.y * b6.y;
        float l7 = q2.x * a7.y + q2.y * b7.y;
        l0 += __shfl_xor(l0, 1); l1 += __shfl_xor(l1, 1); l2 += __shfl_xor(l2, 1); l3 += __shfl_xor(l3, 1);
        l4 += __shfl_xor(l4, 1); l5 += __shfl_xor(l5, 1); l6 += __shfl_xor(l6, 1); l7 += __shfl_xor(l7, 1);
        l0 += __shfl_xor(l0, 2); l1 += __shfl_xor(l1, 2); l2 += __shfl_xor(l2, 2); l3 += __shfl_xor(l3, 2);
        l4 += __shfl_xor(l4, 2); l5 += __shfl_xor(l5, 2); l6 += __shfl_xor(l6, 2); l7 += __shfl_xor(l7, 2);
        l0 += __shfl_xor(l0, 4); l1 += __shfl_xor(l1, 4); l2 += __shfl_xor(l2, 4); l3 += __shfl_xor(l3, 4);
        l4 += __shfl_xor(l4, 4); l5 += __shfl_xor(l5, 4); l6 += __shfl_xor(l6, 4); l7 += __shfl_xor(l7, 4);
        float mx = fmaxf(fmaxf(fmaxf(l0, l1), fmaxf(l2, l3)), fmaxf(fmaxf(l4, l5), fmaxf(l6, l7)));
        if (mx > m) {                         // rescale once per 8-edge chunk
            float corr = __expf(m - mx);      // 0 on first chunk (m=-inf)
            s *= corr;
            acc.x *= corr;
            acc.y *= corr;
            m = mx;
        }
        float e0 = __expf(l0 - m), e1 = __expf(l1 - m), e2 = __expf(l2 - m), e3 = __expf(l3 - m);
        float e4 = __expf(l4 - m), e5 = __expf(l5 - m), e6 = __expf(l6 - m), e7 = __expf(l7 - m);
        s += ((e0 + e1) + (e2 + e3)) + ((e4 + e5) + (e6 + e7));
        acc.x += ((e0 * a0.x + e1 * a1.x) + (e2 * a2.x + e3 * a3.x)) + ((e4 * a4.x + e5 * a5.x) + (e6 * a6.x + e7 * a7.x));
        acc.y += ((e0 * b0.x + e1 * b1.x) + (e2 * b2.x + e3 * b3.x)) + ((e4 * b4.x + e5 * b5.x) + (e6 * b6.x + e7 * b7.x));
    }
    for (; i < i1; ++i) {
        int c0 = RFL(col[i]);
        uint2 u0 = kv2[((size_t)c0 << 6) + lane];
        float2 a0 = bf2_unpack(u0.x), b0 = bf2_unpack(u0.y);
        float l0 = q2.x * a0.y + q2.y * b0.y;
        l0 += __shfl_xor(l0, 1);
        l0 += __shfl_xor(l0, 2);
        l0 += __shfl_xor(l0, 4);
        if (l0 > m) {
            float corr = __expf(m - l0);
            s *= corr;
            acc.x *= corr;
            acc.y *= corr;
            m = l0;
        }
        float e0 = __expf(l0 - m);
        s += e0;
        acc.x += e0 * a0.x;
        acc.y += e0 * b0.x;
    }
    float inv = 1.f / fmaxf(s, 1e-16f);
    uint* orow = io + (size_t)wid * 64 + lane;
    float2 o2 = bf2_unpack(*orow);               // skip connection already there
    o2.x += acc.x * inv;
    o2.y += acc.y * inv;
    *orow = bf2_pack(o2.x, o2.y);
}

// ---------------- mean-pool per graph (batch sorted), bf16 in, 64 nodes/block ----------------
__global__ __launch_bounds__(128) void k_pool(const __hip_bfloat16* __restrict__ x, const int* __restrict__ batch,
                                              float* __restrict__ gsum, float* __restrict__ cnt, int n) {
    int t = threadIdx.x;
    int start = blockIdx.x * 64;
    int end = start + 64; if (end > n) end = n;
    if (start >= n) return;
    int cur = batch[start];
    float acc = 0.f;
    int run = 0;
    for (int nn = start; nn < end; ++nn) {
        int g = batch[nn];
        if (g != cur) {
            atomicAdd(&gsum[cur * 128 + t], acc);
            if (t == 0) atomicAdd(&cnt[cur], (float)run);
            acc = 0.f; run = 0; cur = g;
        }
        acc += __bfloat162float(x[(size_t)nn * 128 + t]);
        run++;
    }
    atomicAdd(&gsum[cur * 128 + t], acc);
    if (t == 0) atomicAdd(&cnt[cur], (float)run);
}

// ---------------- FiLM + LSTM + LayerNorm + dueling heads, one block per graph ----------------
__global__ __launch_bounds__(128) void k_final(
    const float* __restrict__ gsum, const float* __restrict__ cnt, const float* __restrict__ w,
    const float* __restrict__ Wgam, const float* __restrict__ bgam,
    const float* __restrict__ Wbet, const float* __restrict__ bbet,
    const float* __restrict__ hprev, const float* __restrict__ cprev,
    const float* __restrict__ Wih, const float* __restrict__ bih,
    const float* __restrict__ Whh, const float* __restrict__ bhh,
    const float* __restrict__ lng, const float* __restrict__ lnb,
    const float* __restrict__ Wa1, const float* __restrict__ ba1,
    const float* __restrict__ Wa2, const float* __restrict__ ba2,
    const float* __restrict__ Wv1, const float* __restrict__ bv1,
    const float* __restrict__ Wv2, const float* __restrict__ bv2,
    float* __restrict__ out_qv, float* __restrict__ out_h, float* __restrict__ out_c) {
    int g = blockIdx.x, t = threadIdx.x;
    __shared__ __align__(16) float ge[128], hp[128], hn[128], r1[128], a1s[128], red[128];
    __shared__ float adv[16], val[2], mu_s, var_s;

    float w0 = w[g * 2 + 0], w1 = w[g * 2 + 1];
    float c = fmaxf(cnt[g], 1.f);
    float mn = gsum[g * 128 + t] / c;
    float gam = w0 * Wgam[2 * t] + w1 * Wgam[2 * t + 1] + bgam[t];
    float bet = w0 * Wbet[2 * t] + w1 * Wbet[2 * t + 1] + bbet[t];
    ge[t] = (1.f + gam) * mn + bet;
    hp[t] = hprev[g * 128 + t];
    __syncthreads();

    float gi = bih[t] + bhh[t];
    float gf = bih[128 + t] + bhh[128 + t];
    float gg = bih[256 + t] + bhh[256 + t];
    float go = bih[384 + t] + bhh[384 + t];
    {
        const float4* ge4 = (const float4*)ge;
        const float4* hp4 = (const float4*)hp;
        const float4* Ai = (const float4*)(Wih + (size_t)t * 128);
        const float4* Af = (const float4*)(Wih + (size_t)(128 + t) * 128);
        const float4* Ag = (const float4*)(Wih + (size_t)(256 + t) * 128);
        const float4* Ao = (const float4*)(Wih + (size_t)(384 + t) * 128);
        const float4* Hi = (const float4*)(Whh + (size_t)t * 128);
        const float4* Hf = (const float4*)(Whh + (size_t)(128 + t) * 128);
        const float4* Hg = (const float4*)(Whh + (size_t)(256 + t) * 128);
        const float4* Ho = (const float4*)(Whh + (size_t)(384 + t) * 128);
        #pragma unroll 4
        for (int k4 = 0; k4 < 32; ++k4) {
            float4 a = ge4[k4], h4 = hp4[k4], u;
            u = Ai[k4]; gi += a.x * u.x + a.y * u.y + a.z * u.z + a.w * u.w;
            u = Hi[k4]; gi += h4.x * u.x + h4.y * u.y + h4.z * u.z + h4.w * u.w;
            u = Af[k4]; gf += a.x * u.x + a.y * u.y + a.z * u.z + a.w * u.w;
            u = Hf[k4]; gf += h4.x * u.x + h4.y * u.y + h4.z * u.z + h4.w * u.w;
            u = Ag[k4]; gg += a.x * u.x + a.y * u.y + a.z * u.z + a.w * u.w;
            u = Hg[k4]; gg += h4.x * u.x + h4.y * u.y + h4.z * u.z + h4.w * u.w;
            u = Ao[k4]; go += a.x * u.x + a.y * u.y + a.z * u.z + a.w * u.w;
            u = Ho[k4]; go += h4.x * u.x + h4.y * u.y + h4.z * u.z + h4.w * u.w;
        }
    }
    float ig = 1.f / (1.f + __expf(-gi));
    float fg = 1.f / (1.f + __expf(-gf));
    float gc = tanhf(gg);
    float og = 1.f / (1.f + __expf(-go));
    float craw = fg * cprev[g * 128 + t] + ig * gc;
    float hraw = og * tanhf(craw);
    out_c[g * 128 + t] = fminf(fmaxf(craw, -1e6f), 1e6f);

    red[t] = hraw;
    __syncthreads();
    for (int s2 = 64; s2 > 0; s2 >>= 1) { if (t < s2) red[t] += red[t + s2]; __syncthreads(); }
    if (t == 0) mu_s = red[0] * (1.f / 128.f);
    __syncthreads();
    float mu = mu_s;
    float d = hraw - mu;
    red[t] = d * d;
    __syncthreads();
    for (int s2 = 64; s2 > 0; s2 >>= 1) { if (t < s2) red[t] += red[t + s2]; __syncthreads(); }
    if (t == 0) var_s = red[0] * (1.f / 128.f);
    __syncthreads();
    float hv = d * rsqrtf(var_s + 1e-5f) * lng[t] + lnb[t];
    hn[t] = hv;
    out_h[g * 128 + t] = hv;
    __syncthreads();

    float accv = bv1[t], acca = ba1[t];
    {
        const float4* hn4 = (const float4*)hn;
        const float4* V1 = (const float4*)(Wv1 + (size_t)t * 128);
        const float4* A1 = (const float4*)(Wa1 + (size_t)t * 128);
        #pragma unroll 4
        for (int k4 = 0; k4 < 32; ++k4) {
            float4 hh = hn4[k4], u;
            u = V1[k4]; accv += hh.x * u.x + hh.y * u.y + hh.z * u.z + hh.w * u.w;
            u = A1[k4]; acca += hh.x * u.x + hh.y * u.y + hh.z * u.z + hh.w * u.w;
        }
    }
    r1[t] = fmaxf(accv, 0.f);
    a1s[t] = fmaxf(acca, 0.f);
    __syncthreads();
    if (t < 2) {
        float s = bv2[t];
        const float4* V2 = (const float4*)(Wv2 + (size_t)t * 128);
        const float4* r4 = (const float4*)r1;
        for (int k4 = 0; k4 < 32; ++k4) { float4 u = V2[k4], rr = r4[k4]; s += rr.x * u.x + rr.y * u.y + rr.z * u.z + rr.w * u.w; }
        val[t] = s;
    }
    if (t < 14) {
        float s = ba2[t];
        const float4* A2 = (const float4*)(Wa2 + (size_t)t * 128);
        const float4* a4 = (const float4*)a1s;
        for (int k4 = 0; k4 < 32; ++k4) { float4 u = A2[k4], aa = a4[k4]; s += aa.x * u.x + aa.y * u.y + aa.z * u.z + aa.w * u.w; }
        adv[t] = s;
    }
    __syncthreads();
    if (t < 14) {
        int o = t & 1;
        float mo = (adv[o] + adv[o + 2] + adv[o + 4] + adv[o + 6] + adv[o + 8] + adv[o + 10] + adv[o + 12]) * (1.f / 7.f);
        float qq = val[o] + adv[t] - mo;
        if (isnan(qq)) qq = 0.f;
        qq = fminf(fmaxf(qq, -100.f), 100.f);
        out_qv[g * 14 + t] = qq;
    }
}

extern "C" void kernel_launch(void* const* d_in, const int* in_sizes, int n_in,
                              void* d_out, int out_size, void* d_ws, size_t ws_size,
                              hipStream_t stream) {
    const float* nf    = (const float*)d_in[0];
    const int*   ei    = (const int*)d_in[1];
    const int*   batch = (const int*)d_in[2];
    const float* w     = (const float*)d_in[3];
    const float* hprev = (const float*)d_in[4];
    const float* cprev = (const float*)d_in[5];
    const float* W_emb = (const float*)d_in[6];  const float* b_emb = (const float*)d_in[7];
    const float* W_g1  = (const float*)d_in[8];  const float* b_g1  = (const float*)d_in[9];
    const float* W_g2  = (const float*)d_in[10]; const float* b_g2  = (const float*)d_in[11];
    const float* Wq    = (const float*)d_in[12]; const float* bq    = (const float*)d_in[13];
    const float* Wk    = (const float*)d_in[14]; const float* bk    = (const float*)d_in[15];
    const float* Wv    = (const float*)d_in[16]; const float* bv    = (const float*)d_in[17];
    const float* Wskip = (const float*)d_in[18]; const float* bskip = (const float*)d_in[19];
    const float* Wgam  = (const float*)d_in[20]; const float* bgam  = (const float*)d_in[21];
    const float* Wbet  = (const float*)d_in[22]; const float* bbet  = (const float*)d_in[23];
    const float* Wih   = (const float*)d_in[24]; const float* bih   = (const float*)d_in[25];
    const float* Whh   = (const float*)d_in[26]; const float* bhh   = (const float*)d_in[27];
    const float* lng   = (const float*)d_in[28]; const float* lnb   = (const float*)d_in[29];
    const float* Wa1   = (const float*)d_in[30]; const float* ba1   = (const float*)d_in[31];
    const float* Wa2   = (const float*)d_in[32]; const float* ba2   = (const float*)d_in[33];
    const float* Wv1   = (const float*)d_in[34]; const float* bv1   = (const float*)d_in[35];
    const float* Wv2   = (const float*)d_in[36]; const float* bv2   = (const float*)d_in[37];

    int N = in_sizes[2];
    int E = in_sizes[1] / 2;
    int B = in_sizes[4] / 128;
    int nb = (N + 1023) / 1024;

    char* p = (char*)d_ws;
    auto alloc = [&](size_t bytes) { char* r = p; p += (bytes + 511) & ~(size_t)511; return r; };
    int*   indeg  = (int*)alloc((size_t)N * 4);
    int*   cursor = (int*)alloc((size_t)N * 4);
    float* gsum   = (float*)alloc((size_t)B * 128 * 4);
    float* cnt    = (float*)alloc((size_t)B * 4);
    size_t zbytes = (size_t)(p - (char*)d_ws);   // region zeroed each call
    int*   off    = (int*)alloc((size_t)(N + 1) * 4);
    int*   col    = (int*)alloc((size_t)E * 4);
    float* dinv   = (float*)alloc((size_t)N * 4);
    int*   bsum   = (int*)alloc((size_t)(nb + 1) * 4);
    int*   bexcl  = (int*)alloc((size_t)(nb + 1) * 4);
    __hip_bfloat16* Wc  = (__hip_bfloat16*)alloc((size_t)6 * 16384 * 2);  // bf16 weights: g1,g2,q,k,v,skip
    __hip_bfloat16* X0b = (__hip_bfloat16*)alloc((size_t)N * 128 * 2);    // x0 / x2
    __hip_bfloat16* X1b = (__hip_bfloat16*)alloc((size_t)N * 128 * 2);    // x1
    __hip_bfloat16* XWb = (__hip_bfloat16*)alloc((size_t)N * 128 * 2);    // xw scratch (prescaled)
    uint*  KV  = (uint*)alloc((size_t)N * 128 * 4);                       // packed k|v per feature
    __hip_bfloat16* Cqb = (__hip_bfloat16*)alloc((size_t)N * 128 * 2);    // q bf16 (x0.25)
    __hip_bfloat16* Bb  = (__hip_bfloat16*)alloc((size_t)N * 128 * 2);    // skip + attn out, bf16
    if ((size_t)(p - (char*)d_ws) > ws_size) return;

    hipMemsetAsync(d_ws, 0, zbytes, stream);

    const __hip_bfloat16* Wg1b  = Wc + 0 * 16384;
    const __hip_bfloat16* Wg2b  = Wc + 1 * 16384;
    const __hip_bfloat16* Wqkvs = Wc + 2 * 16384;   // q,k,v,skip contiguous
    k_cvt6<<<384, 256, 0, stream>>>(W_g1, W_g2, Wq, Wk, Wv, Wskip, Wc);

    int gE = (E + 255) / 256;
    k_count<<<gE, 256, 0, stream>>>(ei, indeg, E);
    k_bsum<<<nb, 256, 0, stream>>>(indeg, bsum, N);
    k_scanb<<<1, 256, 0, stream>>>(bsum, bexcl, off, N, nb, E);
    k_scatter<<<nb, 256, 0, stream>>>(indeg, bexcl, off, dinv, N);
    k_fill<<<gE, 256, 0, stream>>>(ei, off, cursor, col, E);

    int gN = (N + 3) / 4;       // gather kernels: 4 waves/block, 1 node/wave
    int gM = (N + 63) / 64;     // MFMA kernels: 64 rows/block

    k_linear<32, true, true, __hip_bfloat16><<<2048, 256, 0, stream>>>(nf, W_emb, b_emb, X0b, N);   // x0 bf16
    k_lin_mfma_scale<<<gM, 256, 0, stream>>>(X0b, Wg1b, dinv, XWb, N);                              // xw1' = xw1*dinv
    k_gcn_agg<<<gN, 256, 0, stream>>>((const uint*)XWb, off, col, dinv, b_g1, (__hip_bfloat162*)X1b, N); // x1
    k_lin_mfma_scale<<<gM, 256, 0, stream>>>(X1b, Wg2b, dinv, XWb, N);                              // xw2'
    k_gcn_agg<<<gN, 256, 0, stream>>>((const uint*)XWb, off, col, dinv, b_g2, (__hip_bfloat162*)X0b, N); // x2

    k_qkvs_mfma<<<gM, 256, 0, stream>>>(X0b, Wqkvs, bq, bk, bv, bskip, Cqb, KV, Bb, N);             // q,KV,skip
    k_attn<<<gN, 256, 0, stream>>>((const uint*)Cqb, (const uint2*)KV, off, col, (uint*)Bb, N);     // Bb += attn

    k_pool<<<gM, 128, 0, stream>>>(Bb, batch, gsum, cnt, N);

    float* out_qv = (float*)d_out;
    float* out_h  = out_qv + (size_t)B * 14;
    float* out_c  = out_h + (size_t)B * 128;
    k_final<<<B, 128, 0, stream>>>(gsum, cnt, w, Wgam, bgam, Wbet, bbet, hprev, cprev,
                                   Wih, bih, Whh, bhh, lng, lnb,
                                   Wa1, ba1, Wa2, ba2, Wv1, bv1, Wv2, bv2,
                                   out_qv, out_h, out_c);
}

// Round 10
// 548.383 us; speedup vs baseline: 1.2269x; 1.0104x over previous
//
#include <hip/hip_runtime.h>
#include <hip/hip_bf16.h>
#include <math.h>

typedef unsigned int uint;
typedef __bf16 bf16_t;
typedef bf16_t bf16x8 __attribute__((ext_vector_type(8)));
typedef float f32x4 __attribute__((ext_vector_type(4)));

__device__ inline float2 bf2_unpack(uint u) {
    union { uint i; float f; } a, b;
    a.i = u << 16;
    b.i = u & 0xffff0000u;
    return make_float2(a.f, b.f);   // (lo, hi)
}

__device__ inline uint bf2_pack(float lo, float hi) {
    __hip_bfloat162 h;
    h.x = __float2bfloat16(lo);
    h.y = __float2bfloat16(hi);
    return *(uint*)&h;              // hi<<16 | lo
}

__device__ inline void store_out(float* p, float v) { *p = v; }
__device__ inline void store_out(__hip_bfloat16* p, float v) { *p = __float2bfloat16(v); }

#define RFL(x) __builtin_amdgcn_readfirstlane(x)

// ---------------- CSR build ----------------
__global__ __launch_bounds__(256) void k_count(const int* __restrict__ ei, int* __restrict__ indeg, int E) {
    int e = blockIdx.x * 256 + threadIdx.x;
    if (e < E) atomicAdd(&indeg[ei[E + e]], 1);
}

// per-1024-chunk sums (coalesced int4)
__global__ __launch_bounds__(256) void k_bsum(const int* __restrict__ indeg, int* __restrict__ bsum, int n) {
    __shared__ int sd[256];
    int t = threadIdx.x;
    int base = blockIdx.x * 1024 + t * 4;
    int s = 0;
    if (base + 3 < n) {
        int4 v = *(const int4*)(indeg + base);
        s = v.x + v.y + v.z + v.w;
    } else {
        for (int j = 0; j < 4; ++j) if (base + j < n) s += indeg[base + j];
    }
    sd[t] = s;
    __syncthreads();
    for (int d = 128; d > 0; d >>= 1) { if (t < d) sd[t] += sd[t + d]; __syncthreads(); }
    if (t == 0) bsum[blockIdx.x] = sd[0];
}

// one small block: exclusive scan of block sums; also sets off[n]=E
__global__ __launch_bounds__(256) void k_scanb(const int* __restrict__ bsum, int* __restrict__ bexcl,
                                               int* __restrict__ off, int n, int nb, int E) {
    __shared__ int sd[256];
    int t = threadIdx.x;
    int v = (t < nb) ? bsum[t] : 0;
    sd[t] = v;
    __syncthreads();
    for (int d = 1; d < 256; d <<= 1) {
        int a = (t >= d) ? sd[t - d] : 0;
        __syncthreads();
        sd[t] += a;
        __syncthreads();
    }
    if (t < nb) bexcl[t] = sd[t] - v;
    if (t == 0) off[n] = E;
}

// per-chunk local exclusive scan + scatter off/dinv (coalesced)
__global__ __launch_bounds__(256) void k_scatter(const int* __restrict__ indeg, const int* __restrict__ bexcl,
                                                 int* __restrict__ off, float* __restrict__ dinv, int n) {
    __shared__ int sd[256];
    int t = threadIdx.x;
    int base = blockIdx.x * 1024 + t * 4;
    int4 v = {0, 0, 0, 0};
    bool full = (base + 3 < n);
    if (full) v = *(const int4*)(indeg + base);
    else { for (int j = 0; j < 4; ++j) if (base + j < n) ((int*)&v)[j] = indeg[base + j]; }
    int s = v.x + v.y + v.z + v.w;
    sd[t] = s;
    __syncthreads();
    for (int d = 1; d < 256; d <<= 1) {
        int a = (t >= d) ? sd[t - d] : 0;
        __syncthreads();
        sd[t] += a;
        __syncthreads();
    }
    int run = bexcl[blockIdx.x] + sd[t] - s;
    int4 o;
    o.x = run; run += v.x;
    o.y = run; run += v.y;
    o.z = run; run += v.z;
    o.w = run;
    float4 dv;
    dv.x = rsqrtf((float)(v.x + 1));
    dv.y = rsqrtf((float)(v.y + 1));
    dv.z = rsqrtf((float)(v.z + 1));
    dv.w = rsqrtf((float)(v.w + 1));
    if (full) {
        *(int4*)(off + base) = o;
        *(float4*)(dinv + base) = dv;
    } else {
        for (int j = 0; j < 4; ++j) if (base + j < n) { off[base + j] = ((int*)&o)[j]; dinv[base + j] = ((float*)&dv)[j]; }
    }
}

__global__ __launch_bounds__(256) void k_fill(const int* __restrict__ ei, const int* __restrict__ off,
                                              int* __restrict__ cursor, int* __restrict__ col, int E) {
    int e = blockIdx.x * 256 + threadIdx.x;
    if (e < E) {
        int d = ei[E + e];
        int p = atomicAdd(&cursor[d], 1);
        col[off[d] + p] = ei[e];
    }
}

// ---------------- fp32 -> bf16 weight conversion (6 x 128x128 mats) ----------------
__global__ __launch_bounds__(256) void k_cvt6(const float* __restrict__ s0, const float* __restrict__ s1,
                                              const float* __restrict__ s2, const float* __restrict__ s3,
                                              const float* __restrict__ s4, const float* __restrict__ s5,
                                              __hip_bfloat16* __restrict__ dst) {
    int i = blockIdx.x * 256 + threadIdx.x;
    if (i >= 6 * 16384) return;
    int m = i >> 14;
    const float* s = (m == 0) ? s0 : (m == 1) ? s1 : (m == 2) ? s2 : (m == 3) ? s3 : (m == 4) ? s4 : s5;
    dst[i] = __float2bfloat16(s[i & 16383]);
}

// ---------------- scalar linear for FI=32 (embed), bf16 out ----------------
template<int FI, bool BIAS, bool RELU, typename OUT>
__global__ __launch_bounds__(256) void k_linear(const float* __restrict__ x, const float* __restrict__ W,
                                                const float* __restrict__ b, OUT* __restrict__ y, int n) {
    __shared__ float4 Wt4[(FI / 4) * 128];
    __shared__ float4 xl[2][FI / 4];
    int t = threadIdx.x & 127;
    int h = threadIdx.x >> 7;
    {
        const float4* Wrow = (const float4*)(W + (size_t)t * FI);
        #pragma unroll
        for (int k4 = h * (FI / 8); k4 < (h + 1) * (FI / 8); ++k4) Wt4[k4 * 128 + t] = Wrow[k4];
    }
    float bias = 0.f;
    if (BIAS) bias = b[t];
    __syncthreads();
    for (int n0 = blockIdx.x * 2; n0 < n; n0 += gridDim.x * 2) {
        int nn = n0 + h;
        if (nn < n && t < FI / 4) xl[h][t] = ((const float4*)(x + (size_t)nn * FI))[t];
        __syncthreads();
        if (nn < n) {
            float acc = bias;
            #pragma unroll
            for (int k4 = 0; k4 < FI / 4; ++k4) {
                float4 xv = xl[h][k4];
                float4 wv = Wt4[k4 * 128 + t];
                acc += xv.x * wv.x + xv.y * wv.y + xv.z * wv.z + xv.w * wv.w;
            }
            if (RELU) acc = fmaxf(acc, 0.f);
            store_out(&y[(size_t)nn * 128 + t], acc);
        }
        __syncthreads();
    }
}

// ---------------- MFMA linear with per-row dinv prescale ----------------
__global__ __launch_bounds__(256) void k_lin_mfma_scale(const __hip_bfloat16* __restrict__ X,
                                                        const __hip_bfloat16* __restrict__ W,
                                                        const float* __restrict__ dinv,
                                                        __hip_bfloat16* __restrict__ y, int n) {
    int wave = threadIdx.x >> 6, lane = threadIdx.x & 63;
    int r0 = blockIdx.x * 64 + wave * 16;
    if (r0 >= n) return;
    int mrow = r0 + (lane & 15);
    if (mrow >= n) mrow = n - 1;
    int kk4 = lane >> 4;
    const bf16x8* xr = (const bf16x8*)((const bf16_t*)X + (size_t)mrow * 128);
    bf16x8 a0 = xr[0 * 4 + kk4];
    bf16x8 a1 = xr[1 * 4 + kk4];
    bf16x8 a2 = xr[2 * 4 + kk4];
    bf16x8 a3 = xr[3 * 4 + kk4];
    int orow = (lane >> 4) * 4;
    int ocol = lane & 15;
    float dv[4];
    #pragma unroll
    for (int j = 0; j < 4; ++j) {
        int row = r0 + orow + j;
        dv[j] = (row < n) ? dinv[row] : 0.f;
    }
    #pragma unroll
    for (int c = 0; c < 8; ++c) {
        const bf16x8* wr = (const bf16x8*)((const bf16_t*)W + (size_t)(c * 16 + (lane & 15)) * 128);
        bf16x8 b0 = wr[0 * 4 + kk4];
        bf16x8 b1 = wr[1 * 4 + kk4];
        bf16x8 b2 = wr[2 * 4 + kk4];
        bf16x8 b3 = wr[3 * 4 + kk4];
        f32x4 acc = {0.f, 0.f, 0.f, 0.f};
        acc = __builtin_amdgcn_mfma_f32_16x16x32_bf16(a0, b0, acc, 0, 0, 0);
        acc = __builtin_amdgcn_mfma_f32_16x16x32_bf16(a1, b1, acc, 0, 0, 0);
        acc = __builtin_amdgcn_mfma_f32_16x16x32_bf16(a2, b2, acc, 0, 0, 0);
        acc = __builtin_amdgcn_mfma_f32_16x16x32_bf16(a3, b3, acc, 0, 0, 0);
        int gcol = c * 16 + ocol;
        #pragma unroll
        for (int j = 0; j < 4; ++j) {
            int row = r0 + orow + j;
            if (row < n) store_out(&y[(size_t)row * 128 + gcol], acc[j] * dv[j]);
        }
    }
}

// ---------------- fused q/k/v/skip MFMA ----------------
__global__ __launch_bounds__(256) void k_qkvs_mfma(const __hip_bfloat16* __restrict__ X,
                                                   const __hip_bfloat16* __restrict__ W4,
                                                   const float* __restrict__ bq, const float* __restrict__ bk,
                                                   const float* __restrict__ bv, const float* __restrict__ bs,
                                                   __hip_bfloat16* __restrict__ Cqb, uint* __restrict__ KVp,
                                                   __hip_bfloat16* __restrict__ Bb, int n) {
    int wave = threadIdx.x >> 6, lane = threadIdx.x & 63;
    int r0 = blockIdx.x * 64 + wave * 16;
    if (r0 >= n) return;
    int mrow = r0 + (lane & 15);
    if (mrow >= n) mrow = n - 1;
    int kk4 = lane >> 4;
    const bf16x8* xr = (const bf16x8*)((const bf16_t*)X + (size_t)mrow * 128);
    bf16x8 a0 = xr[0 * 4 + kk4];
    bf16x8 a1 = xr[1 * 4 + kk4];
    bf16x8 a2 = xr[2 * 4 + kk4];
    bf16x8 a3 = xr[3 * 4 + kk4];
    int orow = (lane >> 4) * 4;
    int ocol = lane & 15;
    float karr[32];
    #pragma unroll
    for (int m = 0; m < 4; ++m) {
        const bf16_t* Wm = (const bf16_t*)W4 + (size_t)m * 16384;
        const float* bias = (m == 0) ? bq : (m == 1) ? bk : (m == 2) ? bv : bs;
        #pragma unroll
        for (int c = 0; c < 8; ++c) {
            const bf16x8* wr = (const bf16x8*)(Wm + (size_t)(c * 16 + (lane & 15)) * 128);
            bf16x8 b0 = wr[0 * 4 + kk4];
            bf16x8 b1 = wr[1 * 4 + kk4];
            bf16x8 b2 = wr[2 * 4 + kk4];
            bf16x8 b3 = wr[3 * 4 + kk4];
            f32x4 acc = {0.f, 0.f, 0.f, 0.f};
            acc = __builtin_amdgcn_mfma_f32_16x16x32_bf16(a0, b0, acc, 0, 0, 0);
            acc = __builtin_amdgcn_mfma_f32_16x16x32_bf16(a1, b1, acc, 0, 0, 0);
            acc = __builtin_amdgcn_mfma_f32_16x16x32_bf16(a2, b2, acc, 0, 0, 0);
            acc = __builtin_amdgcn_mfma_f32_16x16x32_bf16(a3, b3, acc, 0, 0, 0);
            int gcol = c * 16 + ocol;
            float bb = bias[gcol];
            #pragma unroll
            for (int j = 0; j < 4; ++j) {
                int row = r0 + orow + j;
                float v = acc[j] + bb;
                if (m == 1) karr[c * 4 + j] = v;
                if (row >= n) continue;
                if (m == 0) store_out(&Cqb[(size_t)row * 128 + gcol], v * 0.25f);
                else if (m == 2) KVp[(size_t)row * 128 + gcol] = bf2_pack(v, karr[c * 4 + j]);  // lo=v, hi=k
                else if (m == 3) store_out(&Bb[(size_t)row * 128 + gcol], v);
            }
        }
    }
}

// ---------------- GCN aggregation: 1 wave/node, ping-pong prefetch (8-edge chunks) ----------------
__device__ __forceinline__ void gcn_load8(const int* __restrict__ col, int i, const uint* __restrict__ xw,
                                          int lane, uint (&u)[8]) {
    #pragma unroll
    for (int j = 0; j < 8; ++j) {
        int c = RFL(col[i + j]);
        u[j] = xw[(size_t)c * 64 + lane];
    }
}

__device__ __forceinline__ void gcn_proc8(const uint (&u)[8], float2& acc) {
    float sx = 0.f, sy = 0.f;
    #pragma unroll
    for (int j = 0; j < 8; ++j) {
        float2 x = bf2_unpack(u[j]);
        sx += x.x;
        sy += x.y;
    }
    acc.x += sx;
    acc.y += sy;
}

__global__ __launch_bounds__(256) void k_gcn_agg(const uint* __restrict__ xw, const int* __restrict__ off,
                                                 const int* __restrict__ col, const float* __restrict__ dinv,
                                                 const float* __restrict__ bias, __hip_bfloat162* __restrict__ y, int n) {
    int wid = RFL((int)((blockIdx.x * 256 + threadIdx.x) >> 6));
    int lane = threadIdx.x & 63;
    if (wid >= n) return;
    float di = dinv[wid];
    float2 acc = bf2_unpack(xw[(size_t)wid * 64 + lane]);  // self (prescaled by its dinv)
    int i = RFL(off[wid]), i1 = RFL(off[wid + 1]);
    uint ua[8], ub[8];
    if (i + 8 <= i1) {
        gcn_load8(col, i, xw, lane, ua);
        while (true) {
            int inext = i + 8;
            bool more = (inext + 8 <= i1);
            if (more) gcn_load8(col, inext, xw, lane, ub);
            gcn_proc8(ua, acc);
            i = inext;
            if (!more) break;
            inext = i + 8;
            more = (inext + 8 <= i1);
            if (more) gcn_load8(col, inext, xw, lane, ua);
            gcn_proc8(ub, acc);
            i = inext;
            if (!more) break;
        }
    }
    for (; i < i1; ++i) {
        int c0 = RFL(col[i]);
        float2 x0 = bf2_unpack(xw[(size_t)c0 * 64 + lane]);
        acc.x += x0.x;
        acc.y += x0.y;
    }
    float2 b2 = ((const float2*)bias)[lane];
    __hip_bfloat162 o;
    o.x = __float2bfloat16(fmaxf(di * acc.x + b2.x, 0.f));
    o.y = __float2bfloat16(fmaxf(di * acc.y + b2.y, 0.f));
    y[(size_t)wid * 64 + lane] = o;
}

// ---------------- transformer attention: 1 wave/dst, packed KV, ping-pong prefetch ----------------
// q bf16 prescaled by 0.25. KV row = 64 uint2 (feat pair: lo=v, hi=k). Lane l covers feats {2l,2l+1}.
// head h = l>>3 spans lanes 8h..8h+7.
__device__ __forceinline__ void attn_load8(const int* __restrict__ col, int i, const uint2* __restrict__ kv2,
                                           int lane, uint2 (&u)[8]) {
    #pragma unroll
    for (int j = 0; j < 8; ++j) {
        int c = RFL(col[i + j]);
        u[j] = kv2[((size_t)c << 6) + lane];
    }
}

__device__ __forceinline__ void attn_proc8(const uint2 (&u)[8], float2 q2,
                                           float& m, float& s, float2& acc) {
    float l[8];
    #pragma unroll
    for (int j = 0; j < 8; ++j) {
        float2 a = bf2_unpack(u[j].x), b = bf2_unpack(u[j].y);
        l[j] = q2.x * a.y + q2.y * b.y;
    }
    #pragma unroll
    for (int j = 0; j < 8; ++j) l[j] += __shfl_xor(l[j], 1);
    #pragma unroll
    for (int j = 0; j < 8; ++j) l[j] += __shfl_xor(l[j], 2);
    #pragma unroll
    for (int j = 0; j < 8; ++j) l[j] += __shfl_xor(l[j], 4);
    float mx = fmaxf(fmaxf(fmaxf(l[0], l[1]), fmaxf(l[2], l[3])), fmaxf(fmaxf(l[4], l[5]), fmaxf(l[6], l[7])));
    if (mx > m) {
        float corr = __expf(m - mx);     // 0 on first chunk (m=-inf)
        s *= corr;
        acc.x *= corr;
        acc.y *= corr;
        m = mx;
    }
    float sx = 0.f, sy = 0.f, ss = 0.f;
    #pragma unroll
    for (int j = 0; j < 8; ++j) {
        float e = __expf(l[j] - m);
        float2 a = bf2_unpack(u[j].x), b = bf2_unpack(u[j].y);
        ss += e;
        sx += e * a.x;
        sy += e * b.x;
    }
    s += ss;
    acc.x += sx;
    acc.y += sy;
}

__global__ __launch_bounds__(256) void k_attn(const uint* __restrict__ qb, const uint2* __restrict__ kv2,
                                              const int* __restrict__ off, const int* __restrict__ col,
                                              uint* __restrict__ io, int n) {
    int wid = RFL((int)((blockIdx.x * 256 + threadIdx.x) >> 6));
    int lane = threadIdx.x & 63;
    if (wid >= n) return;
    float2 q2 = bf2_unpack(qb[(size_t)wid * 64 + lane]);
    float m = -INFINITY, s = 0.f;
    float2 acc = make_float2(0.f, 0.f);
    int i = RFL(off[wid]), i1 = RFL(off[wid + 1]);
    uint2 ua[8], ub[8];
    if (i + 8 <= i1) {
        attn_load8(col, i, kv2, lane, ua);
        while (true) {
            int inext = i + 8;
            bool more = (inext + 8 <= i1);
            if (more) attn_load8(col, inext, kv2, lane, ub);
            attn_proc8(ua, q2, m, s, acc);
            i = inext;
            if (!more) break;
            inext = i + 8;
            more = (inext + 8 <= i1);
            if (more) attn_load8(col, inext, kv2, lane, ua);
            attn_proc8(ub, q2, m, s, acc);
            i = inext;
            if (!more) break;
        }
    }
    for (; i < i1; ++i) {
        int c0 = RFL(col[i]);
        uint2 u0 = kv2[((size_t)c0 << 6) + lane];
        float2 a0 = bf2_unpack(u0.x), b0 = bf2_unpack(u0.y);
        float l0 = q2.x * a0.y + q2.y * b0.y;
        l0 += __shfl_xor(l0, 1);
        l0 += __shfl_xor(l0, 2);
        l0 += __shfl_xor(l0, 4);
        if (l0 > m) {
            float corr = __expf(m - l0);
            s *= corr;
            acc.x *= corr;
            acc.y *= corr;
            m = l0;
        }
        float e0 = __expf(l0 - m);
        s += e0;
        acc.x += e0 * a0.x;
        acc.y += e0 * b0.x;
    }
    float inv = 1.f / fmaxf(s, 1e-16f);
    uint* orow = io + (size_t)wid * 64 + lane;
    float2 o2 = bf2_unpack(*orow);               // skip connection already there
    o2.x += acc.x * inv;
    o2.y += acc.y * inv;
    *orow = bf2_pack(o2.x, o2.y);
}

// ---------------- mean-pool per graph (batch sorted), bf16 in, 64 nodes/block ----------------
__global__ __launch_bounds__(128) void k_pool(const __hip_bfloat16* __restrict__ x, const int* __restrict__ batch,
                                              float* __restrict__ gsum, float* __restrict__ cnt, int n) {
    int t = threadIdx.x;
    int start = blockIdx.x * 64;
    int end = start + 64; if (end > n) end = n;
    if (start >= n) return;
    int cur = batch[start];
    float acc = 0.f;
    int run = 0;
    for (int nn = start; nn < end; ++nn) {
        int g = batch[nn];
        if (g != cur) {
            atomicAdd(&gsum[cur * 128 + t], acc);
            if (t == 0) atomicAdd(&cnt[cur], (float)run);
            acc = 0.f; run = 0; cur = g;
        }
        acc += __bfloat162float(x[(size_t)nn * 128 + t]);
        run++;
    }
    atomicAdd(&gsum[cur * 128 + t], acc);
    if (t == 0) atomicAdd(&cnt[cur], (float)run);
}

// ---------------- FiLM + LSTM + LayerNorm + dueling heads, one block per graph ----------------
__global__ __launch_bounds__(128) void k_final(
    const float* __restrict__ gsum, const float* __restrict__ cnt, const float* __restrict__ w,
    const float* __restrict__ Wgam, const float* __restrict__ bgam,
    const float* __restrict__ Wbet, const float* __restrict__ bbet,
    const float* __restrict__ hprev, const float* __restrict__ cprev,
    const float* __restrict__ Wih, const float* __restrict__ bih,
    const float* __restrict__ Whh, const float* __restrict__ bhh,
    const float* __restrict__ lng, const float* __restrict__ lnb,
    const float* __restrict__ Wa1, const float* __restrict__ ba1,
    const float* __restrict__ Wa2, const float* __restrict__ ba2,
    const float* __restrict__ Wv1, const float* __restrict__ bv1,
    const float* __restrict__ Wv2, const float* __restrict__ bv2,
    float* __restrict__ out_qv, float* __restrict__ out_h, float* __restrict__ out_c) {
    int g = blockIdx.x, t = threadIdx.x;
    __shared__ __align__(16) float ge[128], hp[128], hn[128], r1[128], a1s[128], red[128];
    __shared__ float adv[16], val[2], mu_s, var_s;

    float w0 = w[g * 2 + 0], w1 = w[g * 2 + 1];
    float c = fmaxf(cnt[g], 1.f);
    float mn = gsum[g * 128 + t] / c;
    float gam = w0 * Wgam[2 * t] + w1 * Wgam[2 * t + 1] + bgam[t];
    float bet = w0 * Wbet[2 * t] + w1 * Wbet[2 * t + 1] + bbet[t];
    ge[t] = (1.f + gam) * mn + bet;
    hp[t] = hprev[g * 128 + t];
    __syncthreads();

    float gi = bih[t] + bhh[t];
    float gf = bih[128 + t] + bhh[128 + t];
    float gg = bih[256 + t] + bhh[256 + t];
    float go = bih[384 + t] + bhh[384 + t];
    {
        const float4* ge4 = (const float4*)ge;
        const float4* hp4 = (const float4*)hp;
        const float4* Ai = (const float4*)(Wih + (size_t)t * 128);
        const float4* Af = (const float4*)(Wih + (size_t)(128 + t) * 128);
        const float4* Ag = (const float4*)(Wih + (size_t)(256 + t) * 128);
        const float4* Ao = (const float4*)(Wih + (size_t)(384 + t) * 128);
        const float4* Hi = (const float4*)(Whh + (size_t)t * 128);
        const float4* Hf = (const float4*)(Whh + (size_t)(128 + t) * 128);
        const float4* Hg = (const float4*)(Whh + (size_t)(256 + t) * 128);
        const float4* Ho = (const float4*)(Whh + (size_t)(384 + t) * 128);
        #pragma unroll 4
        for (int k4 = 0; k4 < 32; ++k4) {
            float4 a = ge4[k4], h4 = hp4[k4], u;
            u = Ai[k4]; gi += a.x * u.x + a.y * u.y + a.z * u.z + a.w * u.w;
            u = Hi[k4]; gi += h4.x * u.x + h4.y * u.y + h4.z * u.z + h4.w * u.w;
            u = Af[k4]; gf += a.x * u.x + a.y * u.y + a.z * u.z + a.w * u.w;
            u = Hf[k4]; gf += h4.x * u.x + h4.y * u.y + h4.z * u.z + h4.w * u.w;
            u = Ag[k4]; gg += a.x * u.x + a.y * u.y + a.z * u.z + a.w * u.w;
            u = Hg[k4]; gg += h4.x * u.x + h4.y * u.y + h4.z * u.z + h4.w * u.w;
            u = Ao[k4]; go += a.x * u.x + a.y * u.y + a.z * u.z + a.w * u.w;
            u = Ho[k4]; go += h4.x * u.x + h4.y * u.y + h4.z * u.z + h4.w * u.w;
        }
    }
    float ig = 1.f / (1.f + __expf(-gi));
    float fg = 1.f / (1.f + __expf(-gf));
    float gc = tanhf(gg);
    float og = 1.f / (1.f + __expf(-go));
    float craw = fg * cprev[g * 128 + t] + ig * gc;
    float hraw = og * tanhf(craw);
    out_c[g * 128 + t] = fminf(fmaxf(craw, -1e6f), 1e6f);

    red[t] = hraw;
    __syncthreads();
    for (int s2 = 64; s2 > 0; s2 >>= 1) { if (t < s2) red[t] += red[t + s2]; __syncthreads(); }
    if (t == 0) mu_s = red[0] * (1.f / 128.f);
    __syncthreads();
    float mu = mu_s;
    float d = hraw - mu;
    red[t] = d * d;
    __syncthreads();
    for (int s2 = 64; s2 > 0; s2 >>= 1) { if (t < s2) red[t] += red[t + s2]; __syncthreads(); }
    if (t == 0) var_s = red[0] * (1.f / 128.f);
    __syncthreads();
    float hv = d * rsqrtf(var_s + 1e-5f) * lng[t] + lnb[t];
    hn[t] = hv;
    out_h[g * 128 + t] = hv;
    __syncthreads();

    float accv = bv1[t], acca = ba1[t];
    {
        const float4* hn4 = (const float4*)hn;
        const float4* V1 = (const float4*)(Wv1 + (size_t)t * 128);
        const float4* A1 = (const float4*)(Wa1 + (size_t)t * 128);
        #pragma unroll 4
        for (int k4 = 0; k4 < 32; ++k4) {
            float4 hh = hn4[k4], u;
            u = V1[k4]; accv += hh.x * u.x + hh.y * u.y + hh.z * u.z + hh.w * u.w;
            u = A1[k4]; acca += hh.x * u.x + hh.y * u.y + hh.z * u.z + hh.w * u.w;
        }
    }
    r1[t] = fmaxf(accv, 0.f);
    a1s[t] = fmaxf(acca, 0.f);
    __syncthreads();
    if (t < 2) {
        float s = bv2[t];
        const float4* V2 = (const float4*)(Wv2 + (size_t)t * 128);
        const float4* r4 = (const float4*)r1;
        for (int k4 = 0; k4 < 32; ++k4) { float4 u = V2[k4], rr = r4[k4]; s += rr.x * u.x + rr.y * u.y + rr.z * u.z + rr.w * u.w; }
        val[t] = s;
    }
    if (t < 14) {
        float s = ba2[t];
        const float4* A2 = (const float4*)(Wa2 + (size_t)t * 128);
        const float4* a4 = (const float4*)a1s;
        for (int k4 = 0; k4 < 32; ++k4) { float4 u = A2[k4], aa = a4[k4]; s += aa.x * u.x + aa.y * u.y + aa.z * u.z + aa.w * u.w; }
        adv[t] = s;
    }
    __syncthreads();
    if (t < 14) {
        int o = t & 1;
        float mo = (adv[o] + adv[o + 2] + adv[o + 4] + adv[o + 6] + adv[o + 8] + adv[o + 10] + adv[o + 12]) * (1.f / 7.f);
        float qq = val[o] + adv[t] - mo;
        if (isnan(qq)) qq = 0.f;
        qq = fminf(fmaxf(qq, -100.f), 100.f);
        out_qv[g * 14 + t] = qq;
    }
}

extern "C" void kernel_launch(void* const* d_in, const int* in_sizes, int n_in,
                              void* d_out, int out_size, void* d_ws, size_t ws_size,
                              hipStream_t stream) {
    const float* nf    = (const float*)d_in[0];
    const int*   ei    = (const int*)d_in[1];
    const int*   batch = (const int*)d_in[2];
    const float* w     = (const float*)d_in[3];
    const float* hprev = (const float*)d_in[4];
    const float* cprev = (const float*)d_in[5];
    const float* W_emb = (const float*)d_in[6];  const float* b_emb = (const float*)d_in[7];
    const float* W_g1  = (const float*)d_in[8];  const float* b_g1  = (const float*)d_in[9];
    const float* W_g2  = (const float*)d_in[10]; const float* b_g2  = (const float*)d_in[11];
    const float* Wq    = (const float*)d_in[12]; const float* bq    = (const float*)d_in[13];
    const float* Wk    = (const float*)d_in[14]; const float* bk    = (const float*)d_in[15];
    const float* Wv    = (const float*)d_in[16]; const float* bv    = (const float*)d_in[17];
    const float* Wskip = (const float*)d_in[18]; const float* bskip = (const float*)d_in[19];
    const float* Wgam  = (const float*)d_in[20]; const float* bgam  = (const float*)d_in[21];
    const float* Wbet  = (const float*)d_in[22]; const float* bbet  = (const float*)d_in[23];
    const float* Wih   = (const float*)d_in[24]; const float* bih   = (const float*)d_in[25];
    const float* Whh   = (const float*)d_in[26]; const float* bhh   = (const float*)d_in[27];
    const float* lng   = (const float*)d_in[28]; const float* lnb   = (const float*)d_in[29];
    const float* Wa1   = (const float*)d_in[30]; const float* ba1   = (const float*)d_in[31];
    const float* Wa2   = (const float*)d_in[32]; const float* ba2   = (const float*)d_in[33];
    const float* Wv1   = (const float*)d_in[34]; const float* bv1   = (const float*)d_in[35];
    const float* Wv2   = (const float*)d_in[36]; const float* bv2   = (const float*)d_in[37];

    int N = in_sizes[2];
    int E = in_sizes[1] / 2;
    int B = in_sizes[4] / 128;
    int nb = (N + 1023) / 1024;

    char* p = (char*)d_ws;
    auto alloc = [&](size_t bytes) { char* r = p; p += (bytes + 511) & ~(size_t)511; return r; };
    int*   indeg  = (int*)alloc((size_t)N * 4);
    int*   cursor = (int*)alloc((size_t)N * 4);
    float* gsum   = (float*)alloc((size_t)B * 128 * 4);
    float* cnt    = (float*)alloc((size_t)B * 4);
    size_t zbytes = (size_t)(p - (char*)d_ws);   // region zeroed each call
    int*   off    = (int*)alloc((size_t)(N + 1) * 4);
    int*   col    = (int*)alloc((size_t)E * 4);
    float* dinv   = (float*)alloc((size_t)N * 4);
    int*   bsum   = (int*)alloc((size_t)(nb + 1) * 4);
    int*   bexcl  = (int*)alloc((size_t)(nb + 1) * 4);
    __hip_bfloat16* Wc  = (__hip_bfloat16*)alloc((size_t)6 * 16384 * 2);  // bf16 weights: g1,g2,q,k,v,skip
    __hip_bfloat16* X0b = (__hip_bfloat16*)alloc((size_t)N * 128 * 2);    // x0 / x2
    __hip_bfloat16* X1b = (__hip_bfloat16*)alloc((size_t)N * 128 * 2);    // x1
    __hip_bfloat16* XWb = (__hip_bfloat16*)alloc((size_t)N * 128 * 2);    // xw scratch (prescaled)
    uint*  KV  = (uint*)alloc((size_t)N * 128 * 4);                       // packed k|v per feature
    __hip_bfloat16* Cqb = (__hip_bfloat16*)alloc((size_t)N * 128 * 2);    // q bf16 (x0.25)
    __hip_bfloat16* Bb  = (__hip_bfloat16*)alloc((size_t)N * 128 * 2);    // skip + attn out, bf16
    if ((size_t)(p - (char*)d_ws) > ws_size) return;

    hipMemsetAsync(d_ws, 0, zbytes, stream);

    const __hip_bfloat16* Wg1b  = Wc + 0 * 16384;
    const __hip_bfloat16* Wg2b  = Wc + 1 * 16384;
    const __hip_bfloat16* Wqkvs = Wc + 2 * 16384;   // q,k,v,skip contiguous
    k_cvt6<<<384, 256, 0, stream>>>(W_g1, W_g2, Wq, Wk, Wv, Wskip, Wc);

    int gE = (E + 255) / 256;
    k_count<<<gE, 256, 0, stream>>>(ei, indeg, E);
    k_bsum<<<nb, 256, 0, stream>>>(indeg, bsum, N);
    k_scanb<<<1, 256, 0, stream>>>(bsum, bexcl, off, N, nb, E);
    k_scatter<<<nb, 256, 0, stream>>>(indeg, bexcl, off, dinv, N);
    k_fill<<<gE, 256, 0, stream>>>(ei, off, cursor, col, E);

    int gN = (N + 3) / 4;       // gather kernels: 4 waves/block, 1 node/wave
    int gM = (N + 63) / 64;     // MFMA kernels: 64 rows/block

    k_linear<32, true, true, __hip_bfloat16><<<2048, 256, 0, stream>>>(nf, W_emb, b_emb, X0b, N);   // x0 bf16
    k_lin_mfma_scale<<<gM, 256, 0, stream>>>(X0b, Wg1b, dinv, XWb, N);                              // xw1' = xw1*dinv
    k_gcn_agg<<<gN, 256, 0, stream>>>((const uint*)XWb, off, col, dinv, b_g1, (__hip_bfloat162*)X1b, N); // x1
    k_lin_mfma_scale<<<gM, 256, 0, stream>>>(X1b, Wg2b, dinv, XWb, N);                              // xw2'
    k_gcn_agg<<<gN, 256, 0, stream>>>((const uint*)XWb, off, col, dinv, b_g2, (__hip_bfloat162*)X0b, N); // x2

    k_qkvs_mfma<<<gM, 256, 0, stream>>>(X0b, Wqkvs, bq, bk, bv, bskip, Cqb, KV, Bb, N);             // q,KV,skip
    k_attn<<<gN, 256, 0, stream>>>((const uint*)Cqb, (const uint2*)KV, off, col, (uint*)Bb, N);     // Bb += attn

    k_pool<<<gM, 128, 0, stream>>>(Bb, batch, gsum, cnt, N);

    float* out_qv = (float*)d_out;
    float* out_h  = out_qv + (size_t)B * 14;
    float* out_c  = out_h + (size_t)B * 128;
    k_final<<<B, 128, 0, stream>>>(gsum, cnt, w, Wgam, bgam, Wbet, bbet, hprev, cprev,
                                   Wih, bih, Whh, bhh, lng, lnb,
                                   Wa1, ba1, Wa2, ba2, Wv1, bv1, Wv2, bv2,
                                   out_qv, out_h, out_c);
}

// Round 12
// 486.484 us; speedup vs baseline: 1.3830x; 1.1272x over previous
//
#include <hip/hip_runtime.h>
#include <hip/hip_bf16.h>
#include <math.h>

typedef unsigned int uint;
typedef unsigned short ushort_t;
typedef __bf16 bf16_t;
typedef bf16_t bf16x8 __attribute__((ext_vector_type(8)));
typedef float f32x4 __attribute__((ext_vector_type(4)));
typedef float f32x2 __attribute__((ext_vector_type(2)));

__device__ inline float2 bf2_unpack(uint u) {
    union { uint i; float f; } a, b;
    a.i = u << 16;
    b.i = u & 0xffff0000u;
    return make_float2(a.f, b.f);   // (lo, hi)
}

__device__ inline uint bf2_pack(float lo, float hi) {
    __hip_bfloat162 h;
    h.x = __float2bfloat16(lo);
    h.y = __float2bfloat16(hi);
    return *(uint*)&h;              // hi<<16 | lo
}

// fp8 e4m3 (OCP) pack/unpack via HW converts (word selector must be compile-time const)
template<bool WORD>
__device__ __forceinline__ float2 fp8x2_unpack(uint u) {
    f32x2 r = __builtin_amdgcn_cvt_pk_f32_fp8((int)u, WORD);
    return make_float2(r[0], r[1]);
}
__device__ __forceinline__ int fp8x2_pack(float a, float b) {
    return __builtin_amdgcn_cvt_pk_fp8_f32(a, b, 0, false);  // bytes [a,b] in low 16
}

__device__ inline void store_out(float* p, float v) { *p = v; }
__device__ inline void store_out(__hip_bfloat16* p, float v) { *p = __float2bfloat16(v); }

#define RFL(x) __builtin_amdgcn_readfirstlane(x)

#define SCL_XW 32.f
#define SCL_KV 16.f

// ---------------- CSR build ----------------
__global__ __launch_bounds__(256) void k_count(const int* __restrict__ ei, int* __restrict__ indeg, int E) {
    int e = blockIdx.x * 256 + threadIdx.x;
    if (e < E) atomicAdd(&indeg[ei[E + e]], 1);
}

__global__ __launch_bounds__(256) void k_bsum(const int* __restrict__ indeg, int* __restrict__ bsum, int n) {
    __shared__ int sd[256];
    int t = threadIdx.x;
    int base = blockIdx.x * 1024 + t * 4;
    int s = 0;
    if (base + 3 < n) {
        int4 v = *(const int4*)(indeg + base);
        s = v.x + v.y + v.z + v.w;
    } else {
        for (int j = 0; j < 4; ++j) if (base + j < n) s += indeg[base + j];
    }
    sd[t] = s;
    __syncthreads();
    for (int d = 128; d > 0; d >>= 1) { if (t < d) sd[t] += sd[t + d]; __syncthreads(); }
    if (t == 0) bsum[blockIdx.x] = sd[0];
}

__global__ __launch_bounds__(256) void k_scanb(const int* __restrict__ bsum, int* __restrict__ bexcl,
                                               int* __restrict__ off, int n, int nb, int E) {
    __shared__ int sd[256];
    int t = threadIdx.x;
    int v = (t < nb) ? bsum[t] : 0;
    sd[t] = v;
    __syncthreads();
    for (int d = 1; d < 256; d <<= 1) {
        int a = (t >= d) ? sd[t - d] : 0;
        __syncthreads();
        sd[t] += a;
        __syncthreads();
    }
    if (t < nb) bexcl[t] = sd[t] - v;
    if (t == 0) off[n] = E;
}

__global__ __launch_bounds__(256) void k_scatter(const int* __restrict__ indeg, const int* __restrict__ bexcl,
                                                 int* __restrict__ off, float* __restrict__ dinv, int n) {
    __shared__ int sd[256];
    int t = threadIdx.x;
    int base = blockIdx.x * 1024 + t * 4;
    int4 v = {0, 0, 0, 0};
    bool full = (base + 3 < n);
    if (full) v = *(const int4*)(indeg + base);
    else { for (int j = 0; j < 4; ++j) if (base + j < n) ((int*)&v)[j] = indeg[base + j]; }
    int s = v.x + v.y + v.z + v.w;
    sd[t] = s;
    __syncthreads();
    for (int d = 1; d < 256; d <<= 1) {
        int a = (t >= d) ? sd[t - d] : 0;
        __syncthreads();
        sd[t] += a;
        __syncthreads();
    }
    int run = bexcl[blockIdx.x] + sd[t] - s;
    int4 o;
    o.x = run; run += v.x;
    o.y = run; run += v.y;
    o.z = run; run += v.z;
    o.w = run;
    float4 dv;
    dv.x = rsqrtf((float)(v.x + 1));
    dv.y = rsqrtf((float)(v.y + 1));
    dv.z = rsqrtf((float)(v.z + 1));
    dv.w = rsqrtf((float)(v.w + 1));
    if (full) {
        *(int4*)(off + base) = o;
        *(float4*)(dinv + base) = dv;
    } else {
        for (int j = 0; j < 4; ++j) if (base + j < n) { off[base + j] = ((int*)&o)[j]; dinv[base + j] = ((float*)&dv)[j]; }
    }
}

__global__ __launch_bounds__(256) void k_fill(const int* __restrict__ ei, const int* __restrict__ off,
                                              int* __restrict__ cursor, int* __restrict__ col, int E) {
    int e = blockIdx.x * 256 + threadIdx.x;
    if (e < E) {
        int d = ei[E + e];
        int p = atomicAdd(&cursor[d], 1);
        col[off[d] + p] = ei[e];
    }
}

// ---------------- fp32 -> bf16 weight conversion (6 x 128x128 mats) ----------------
__global__ __launch_bounds__(256) void k_cvt6(const float* __restrict__ s0, const float* __restrict__ s1,
                                              const float* __restrict__ s2, const float* __restrict__ s3,
                                              const float* __restrict__ s4, const float* __restrict__ s5,
                                              __hip_bfloat16* __restrict__ dst) {
    int i = blockIdx.x * 256 + threadIdx.x;
    if (i >= 6 * 16384) return;
    int m = i >> 14;
    const float* s = (m == 0) ? s0 : (m == 1) ? s1 : (m == 2) ? s2 : (m == 3) ? s3 : (m == 4) ? s4 : s5;
    dst[i] = __float2bfloat16(s[i & 16383]);
}

// ---------------- scalar linear for FI=32 (embed), bf16 out ----------------
template<int FI, bool BIAS, bool RELU, typename OUT>
__global__ __launch_bounds__(256) void k_linear(const float* __restrict__ x, const float* __restrict__ W,
                                                const float* __restrict__ b, OUT* __restrict__ y, int n) {
    __shared__ float4 Wt4[(FI / 4) * 128];
    __shared__ float4 xl[2][FI / 4];
    int t = threadIdx.x & 127;
    int h = threadIdx.x >> 7;
    {
        const float4* Wrow = (const float4*)(W + (size_t)t * FI);
        #pragma unroll
        for (int k4 = h * (FI / 8); k4 < (h + 1) * (FI / 8); ++k4) Wt4[k4 * 128 + t] = Wrow[k4];
    }
    float bias = 0.f;
    if (BIAS) bias = b[t];
    __syncthreads();
    for (int n0 = blockIdx.x * 2; n0 < n; n0 += gridDim.x * 2) {
        int nn = n0 + h;
        if (nn < n && t < FI / 4) xl[h][t] = ((const float4*)(x + (size_t)nn * FI))[t];
        __syncthreads();
        if (nn < n) {
            float acc = bias;
            #pragma unroll
            for (int k4 = 0; k4 < FI / 4; ++k4) {
                float4 xv = xl[h][k4];
                float4 wv = Wt4[k4 * 128 + t];
                acc += xv.x * wv.x + xv.y * wv.y + xv.z * wv.z + xv.w * wv.w;
            }
            if (RELU) acc = fmaxf(acc, 0.f);
            store_out(&y[(size_t)nn * 128 + t], acc);
        }
        __syncthreads();
    }
}

// ---------------- MFMA linear with per-row dinv prescale, fp8 x SCL_XW output ----------------
// XW8 row = 128 fp8 bytes; even lane packs (col, col+1) as ushort.
__global__ __launch_bounds__(256) void k_lin_mfma_scale(const __hip_bfloat16* __restrict__ X,
                                                        const __hip_bfloat16* __restrict__ W,
                                                        const float* __restrict__ dinv,
                                                        ushort_t* __restrict__ XW8, int n) {
    int wave = threadIdx.x >> 6, lane = threadIdx.x & 63;
    int r0 = blockIdx.x * 64 + wave * 16;
    if (r0 >= n) return;
    int mrow = r0 + (lane & 15);
    if (mrow >= n) mrow = n - 1;
    int kk4 = lane >> 4;
    const bf16x8* xr = (const bf16x8*)((const bf16_t*)X + (size_t)mrow * 128);
    bf16x8 a0 = xr[0 * 4 + kk4];
    bf16x8 a1 = xr[1 * 4 + kk4];
    bf16x8 a2 = xr[2 * 4 + kk4];
    bf16x8 a3 = xr[3 * 4 + kk4];
    int orow = (lane >> 4) * 4;
    int ocol = lane & 15;
    float dv[4];
    #pragma unroll
    for (int j = 0; j < 4; ++j) {
        int row = r0 + orow + j;
        dv[j] = ((row < n) ? dinv[row] : 0.f) * SCL_XW;
    }
    #pragma unroll
    for (int c = 0; c < 8; ++c) {
        const bf16x8* wr = (const bf16x8*)((const bf16_t*)W + (size_t)(c * 16 + (lane & 15)) * 128);
        bf16x8 b0 = wr[0 * 4 + kk4];
        bf16x8 b1 = wr[1 * 4 + kk4];
        bf16x8 b2 = wr[2 * 4 + kk4];
        bf16x8 b3 = wr[3 * 4 + kk4];
        f32x4 acc = {0.f, 0.f, 0.f, 0.f};
        acc = __builtin_amdgcn_mfma_f32_16x16x32_bf16(a0, b0, acc, 0, 0, 0);
        acc = __builtin_amdgcn_mfma_f32_16x16x32_bf16(a1, b1, acc, 0, 0, 0);
        acc = __builtin_amdgcn_mfma_f32_16x16x32_bf16(a2, b2, acc, 0, 0, 0);
        acc = __builtin_amdgcn_mfma_f32_16x16x32_bf16(a3, b3, acc, 0, 0, 0);
        int gcol = c * 16 + ocol;
        #pragma unroll
        for (int j = 0; j < 4; ++j) {
            int row = r0 + orow + j;
            float v = acc[j] * dv[j];
            float vnb = __shfl_down(v, 1);
            if (((lane & 1) == 0) && row < n) {
                int pk = fp8x2_pack(v, vnb);
                XW8[(size_t)row * 64 + (gcol >> 1)] = (ushort_t)(pk & 0xffff);
            }
        }
    }
}

// ---------------- fused q/k/v/skip MFMA ----------------
// q -> Cqb bf16 (x 0.25/SCL_KV); k,v -> KV8 fp8 x SCL_KV, uint per feat-pair [k0,v0,k1,v1]; skip -> Bb bf16
__global__ __launch_bounds__(256) void k_qkvs_mfma(const __hip_bfloat16* __restrict__ X,
                                                   const __hip_bfloat16* __restrict__ W4,
                                                   const float* __restrict__ bq, const float* __restrict__ bk,
                                                   const float* __restrict__ bv, const float* __restrict__ bs,
                                                   __hip_bfloat16* __restrict__ Cqb, uint* __restrict__ KV8,
                                                   __hip_bfloat16* __restrict__ Bb, int n) {
    int wave = threadIdx.x >> 6, lane = threadIdx.x & 63;
    int r0 = blockIdx.x * 64 + wave * 16;
    if (r0 >= n) return;
    int mrow = r0 + (lane & 15);
    if (mrow >= n) mrow = n - 1;
    int kk4 = lane >> 4;
    const bf16x8* xr = (const bf16x8*)((const bf16_t*)X + (size_t)mrow * 128);
    bf16x8 a0 = xr[0 * 4 + kk4];
    bf16x8 a1 = xr[1 * 4 + kk4];
    bf16x8 a2 = xr[2 * 4 + kk4];
    bf16x8 a3 = xr[3 * 4 + kk4];
    int orow = (lane >> 4) * 4;
    int ocol = lane & 15;
    float karr[32];
    #pragma unroll
    for (int m = 0; m < 4; ++m) {
        const bf16_t* Wm = (const bf16_t*)W4 + (size_t)m * 16384;
        const float* bias = (m == 0) ? bq : (m == 1) ? bk : (m == 2) ? bv : bs;
        #pragma unroll
        for (int c = 0; c < 8; ++c) {
            const bf16x8* wr = (const bf16x8*)(Wm + (size_t)(c * 16 + (lane & 15)) * 128);
            bf16x8 b0 = wr[0 * 4 + kk4];
            bf16x8 b1 = wr[1 * 4 + kk4];
            bf16x8 b2 = wr[2 * 4 + kk4];
            bf16x8 b3 = wr[3 * 4 + kk4];
            f32x4 acc = {0.f, 0.f, 0.f, 0.f};
            acc = __builtin_amdgcn_mfma_f32_16x16x32_bf16(a0, b0, acc, 0, 0, 0);
            acc = __builtin_amdgcn_mfma_f32_16x16x32_bf16(a1, b1, acc, 0, 0, 0);
            acc = __builtin_amdgcn_mfma_f32_16x16x32_bf16(a2, b2, acc, 0, 0, 0);
            acc = __builtin_amdgcn_mfma_f32_16x16x32_bf16(a3, b3, acc, 0, 0, 0);
            int gcol = c * 16 + ocol;
            float bb = bias[gcol];
            #pragma unroll
            for (int j = 0; j < 4; ++j) {
                int row = r0 + orow + j;
                float v = acc[j] + bb;
                if (m == 1) karr[c * 4 + j] = v * SCL_KV;
                if (m == 0) {
                    if (row < n) store_out(&Cqb[(size_t)row * 128 + gcol], v * (0.25f / SCL_KV));
                } else if (m == 2) {
                    int pk = fp8x2_pack(karr[c * 4 + j], v * SCL_KV);   // [k, v] low 16
                    int nb = __shfl_down(pk, 1);
                    if (((lane & 1) == 0) && row < n) {
                        uint u = (uint)(pk & 0xffff) | ((uint)nb << 16);
                        KV8[(size_t)row * 64 + (gcol >> 1)] = u;
                    }
                } else if (m == 3) {
                    if (row < n) store_out(&Bb[(size_t)row * 128 + gcol], v);
                }
            }
        }
    }
}

// ---------------- GCN aggregation: 1 wave/node, fp8 payload, ping-pong prefetch ----------------
__device__ __forceinline__ void gcn_load8(const int* __restrict__ col, int i, const ushort_t* __restrict__ xw,
                                          int lane, uint (&u)[8]) {
    #pragma unroll
    for (int j = 0; j < 8; ++j) {
        int c = RFL(col[i + j]);
        u[j] = (uint)xw[(size_t)c * 64 + lane];
    }
}

__device__ __forceinline__ void gcn_proc8(const uint (&u)[8], float2& acc) {
    float sx = 0.f, sy = 0.f;
    #pragma unroll
    for (int j = 0; j < 8; ++j) {
        float2 x = fp8x2_unpack<false>(u[j]);
        sx += x.x;
        sy += x.y;
    }
    acc.x += sx;
    acc.y += sy;
}

__global__ __launch_bounds__(256) void k_gcn_agg(const ushort_t* __restrict__ xw, const int* __restrict__ off,
                                                 const int* __restrict__ col, const float* __restrict__ dinv,
                                                 const float* __restrict__ bias, __hip_bfloat162* __restrict__ y, int n) {
    int wid = RFL((int)((blockIdx.x * 256 + threadIdx.x) >> 6));
    int lane = threadIdx.x & 63;
    if (wid >= n) return;
    float di = dinv[wid] * (1.f / SCL_XW);
    float2 acc = fp8x2_unpack<false>((uint)xw[(size_t)wid * 64 + lane]);
    int i = RFL(off[wid]), i1 = RFL(off[wid + 1]);
    uint ua[8], ub[8];
    if (i + 8 <= i1) {
        gcn_load8(col, i, xw, lane, ua);
        while (true) {
            int inext = i + 8;
            bool more = (inext + 8 <= i1);
            if (more) gcn_load8(col, inext, xw, lane, ub);
            gcn_proc8(ua, acc);
            i = inext;
            if (!more) break;
            inext = i + 8;
            more = (inext + 8 <= i1);
            if (more) gcn_load8(col, inext, xw, lane, ua);
            gcn_proc8(ub, acc);
            i = inext;
            if (!more) break;
        }
    }
    for (; i < i1; ++i) {
        int c0 = RFL(col[i]);
        float2 x0 = fp8x2_unpack<false>((uint)xw[(size_t)c0 * 64 + lane]);
        acc.x += x0.x;
        acc.y += x0.y;
    }
    float2 b2 = ((const float2*)bias)[lane];
    __hip_bfloat162 o;
    o.x = __float2bfloat16(fmaxf(di * acc.x + b2.x, 0.f));
    o.y = __float2bfloat16(fmaxf(di * acc.y + b2.y, 0.f));
    y[(size_t)wid * 64 + lane] = o;
}

// ---------------- transformer attention: 1 wave/dst, fp8 KV, ping-pong prefetch ----------------
// q bf16 prescaled 0.25/SCL_KV. KV8 row = 64 uints: lane l -> [k(2l),v(2l),k(2l+1),v(2l+1)] fp8 x SCL_KV.
// head h = l>>3 spans lanes 8h..8h+7.
__device__ __forceinline__ void attn_load8(const int* __restrict__ col, int i, const uint* __restrict__ kv8,
                                           int lane, uint (&u)[8]) {
    #pragma unroll
    for (int j = 0; j < 8; ++j) {
        int c = RFL(col[i + j]);
        u[j] = kv8[((size_t)c << 6) + lane];
    }
}

__device__ __forceinline__ void attn_proc8(const uint (&u)[8], float2 q2,
                                           float& m, float& s, float2& acc) {
    float l[8];
    #pragma unroll
    for (int j = 0; j < 8; ++j) {
        float2 p0 = fp8x2_unpack<false>(u[j]);  // (k0, v0)
        float2 p1 = fp8x2_unpack<true>(u[j]);   // (k1, v1)
        l[j] = q2.x * p0.x + q2.y * p1.x;
    }
    #pragma unroll
    for (int j = 0; j < 8; ++j) l[j] += __shfl_xor(l[j], 1);
    #pragma unroll
    for (int j = 0; j < 8; ++j) l[j] += __shfl_xor(l[j], 2);
    #pragma unroll
    for (int j = 0; j < 8; ++j) l[j] += __shfl_xor(l[j], 4);
    float mx = fmaxf(fmaxf(fmaxf(l[0], l[1]), fmaxf(l[2], l[3])), fmaxf(fmaxf(l[4], l[5]), fmaxf(l[6], l[7])));
    if (mx > m) {
        float corr = __expf(m - mx);     // 0 on first chunk (m=-inf)
        s *= corr;
        acc.x *= corr;
        acc.y *= corr;
        m = mx;
    }
    float sx = 0.f, sy = 0.f, ss = 0.f;
    #pragma unroll
    for (int j = 0; j < 8; ++j) {
        float e = __expf(l[j] - m);
        float2 p0 = fp8x2_unpack<false>(u[j]);
        float2 p1 = fp8x2_unpack<true>(u[j]);
        ss += e;
        sx += e * p0.y;
        sy += e * p1.y;
    }
    s += ss;
    acc.x += sx;
    acc.y += sy;
}

__global__ __launch_bounds__(256) void k_attn(const uint* __restrict__ qb, const uint* __restrict__ kv8,
                                              const int* __restrict__ off, const int* __restrict__ col,
                                              uint* __restrict__ io, int n) {
    int wid = RFL((int)((blockIdx.x * 256 + threadIdx.x) >> 6));
    int lane = threadIdx.x & 63;
    if (wid >= n) return;
    float2 q2 = bf2_unpack(qb[(size_t)wid * 64 + lane]);
    float m = -INFINITY, s = 0.f;
    float2 acc = make_float2(0.f, 0.f);
    int i = RFL(off[wid]), i1 = RFL(off[wid + 1]);
    uint ua[8], ub[8];
    if (i + 8 <= i1) {
        attn_load8(col, i, kv8, lane, ua);
        while (true) {
            int inext = i + 8;
            bool more = (inext + 8 <= i1);
            if (more) attn_load8(col, inext, kv8, lane, ub);
            attn_proc8(ua, q2, m, s, acc);
            i = inext;
            if (!more) break;
            inext = i + 8;
            more = (inext + 8 <= i1);
            if (more) attn_load8(col, inext, kv8, lane, ua);
            attn_proc8(ub, q2, m, s, acc);
            i = inext;
            if (!more) break;
        }
    }
    for (; i < i1; ++i) {
        int c0 = RFL(col[i]);
        uint u0 = kv8[((size_t)c0 << 6) + lane];
        float2 p0 = fp8x2_unpack<false>(u0);
        float2 p1 = fp8x2_unpack<true>(u0);
        float l0 = q2.x * p0.x + q2.y * p1.x;
        l0 += __shfl_xor(l0, 1);
        l0 += __shfl_xor(l0, 2);
        l0 += __shfl_xor(l0, 4);
        if (l0 > m) {
            float corr = __expf(m - l0);
            s *= corr;
            acc.x *= corr;
            acc.y *= corr;
            m = l0;
        }
        float e0 = __expf(l0 - m);
        s += e0;
        acc.x += e0 * p0.y;
        acc.y += e0 * p1.y;
    }
    float inv = (1.f / SCL_KV) / fmaxf(s, 1e-16f);
    uint* orow = io + (size_t)wid * 64 + lane;
    float2 o2 = bf2_unpack(*orow);               // skip connection already there
    o2.x += acc.x * inv;
    o2.y += acc.y * inv;
    *orow = bf2_pack(o2.x, o2.y);
}

// ---------------- mean-pool per graph (batch sorted), bf16 in, 64 nodes/block ----------------
__global__ __launch_bounds__(128) void k_pool(const __hip_bfloat16* __restrict__ x, const int* __restrict__ batch,
                                              float* __restrict__ gsum, float* __restrict__ cnt, int n) {
    int t = threadIdx.x;
    int start = blockIdx.x * 64;
    int end = start + 64; if (end > n) end = n;
    if (start >= n) return;
    int cur = batch[start];
    float acc = 0.f;
    int run = 0;
    for (int nn = start; nn < end; ++nn) {
        int g = batch[nn];
        if (g != cur) {
            atomicAdd(&gsum[cur * 128 + t], acc);
            if (t == 0) atomicAdd(&cnt[cur], (float)run);
            acc = 0.f; run = 0; cur = g;
        }
        acc += __bfloat162float(x[(size_t)nn * 128 + t]);
        run++;
    }
    atomicAdd(&gsum[cur * 128 + t], acc);
    if (t == 0) atomicAdd(&cnt[cur], (float)run);
}

// ---------------- FiLM + LSTM + LayerNorm + dueling heads, one block per graph ----------------
__global__ __launch_bounds__(128) void k_final(
    const float* __restrict__ gsum, const float* __restrict__ cnt, const float* __restrict__ w,
    const float* __restrict__ Wgam, const float* __restrict__ bgam,
    const float* __restrict__ Wbet, const float* __restrict__ bbet,
    const float* __restrict__ hprev, const float* __restrict__ cprev,
    const float* __restrict__ Wih, const float* __restrict__ bih,
    const float* __restrict__ Whh, const float* __restrict__ bhh,
    const float* __restrict__ lng, const float* __restrict__ lnb,
    const float* __restrict__ Wa1, const float* __restrict__ ba1,
    const float* __restrict__ Wa2, const float* __restrict__ ba2,
    const float* __restrict__ Wv1, const float* __restrict__ bv1,
    const float* __restrict__ Wv2, const float* __restrict__ bv2,
    float* __restrict__ out_qv, float* __restrict__ out_h, float* __restrict__ out_c) {
    int g = blockIdx.x, t = threadIdx.x;
    __shared__ __align__(16) float ge[128], hp[128], hn[128], r1[128], a1s[128], red[128];
    __shared__ float adv[16], val[2], mu_s, var_s;

    float w0 = w[g * 2 + 0], w1 = w[g * 2 + 1];
    float c = fmaxf(cnt[g], 1.f);
    float mn = gsum[g * 128 + t] / c;
    float gam = w0 * Wgam[2 * t] + w1 * Wgam[2 * t + 1] + bgam[t];
    float bet = w0 * Wbet[2 * t] + w1 * Wbet[2 * t + 1] + bbet[t];
    ge[t] = (1.f + gam) * mn + bet;
    hp[t] = hprev[g * 128 + t];
    __syncthreads();

    float gi = bih[t] + bhh[t];
    float gf = bih[128 + t] + bhh[128 + t];
    float gg = bih[256 + t] + bhh[256 + t];
    float go = bih[384 + t] + bhh[384 + t];
    {
        const float4* ge4 = (const float4*)ge;
        const float4* hp4 = (const float4*)hp;
        const float4* Ai = (const float4*)(Wih + (size_t)t * 128);
        const float4* Af = (const float4*)(Wih + (size_t)(128 + t) * 128);
        const float4* Ag = (const float4*)(Wih + (size_t)(256 + t) * 128);
        const float4* Ao = (const float4*)(Wih + (size_t)(384 + t) * 128);
        const float4* Hi = (const float4*)(Whh + (size_t)t * 128);
        const float4* Hf = (const float4*)(Whh + (size_t)(128 + t) * 128);
        const float4* Hg = (const float4*)(Whh + (size_t)(256 + t) * 128);
        const float4* Ho = (const float4*)(Whh + (size_t)(384 + t) * 128);
        #pragma unroll 4
        for (int k4 = 0; k4 < 32; ++k4) {
            float4 a = ge4[k4], h4 = hp4[k4], u;
            u = Ai[k4]; gi += a.x * u.x + a.y * u.y + a.z * u.z + a.w * u.w;
            u = Hi[k4]; gi += h4.x * u.x + h4.y * u.y + h4.z * u.z + h4.w * u.w;
            u = Af[k4]; gf += a.x * u.x + a.y * u.y + a.z * u.z + a.w * u.w;
            u = Hf[k4]; gf += h4.x * u.x + h4.y * u.y + h4.z * u.z + h4.w * u.w;
            u = Ag[k4]; gg += a.x * u.x + a.y * u.y + a.z * u.z + a.w * u.w;
            u = Hg[k4]; gg += h4.x * u.x + h4.y * u.y + h4.z * u.z + h4.w * u.w;
            u = Ao[k4]; go += a.x * u.x + a.y * u.y + a.z * u.z + a.w * u.w;
            u = Ho[k4]; go += h4.x * u.x + h4.y * u.y + h4.z * u.z + h4.w * u.w;
        }
    }
    float ig = 1.f / (1.f + __expf(-gi));
    float fg = 1.f / (1.f + __expf(-gf));
    float gc = tanhf(gg);
    float og = 1.f / (1.f + __expf(-go));
    float craw = fg * cprev[g * 128 + t] + ig * gc;
    float hraw = og * tanhf(craw);
    out_c[g * 128 + t] = fminf(fmaxf(craw, -1e6f), 1e6f);

    red[t] = hraw;
    __syncthreads();
    for (int s2 = 64; s2 > 0; s2 >>= 1) { if (t < s2) red[t] += red[t + s2]; __syncthreads(); }
    if (t == 0) mu_s = red[0] * (1.f / 128.f);
    __syncthreads();
    float mu = mu_s;
    float d = hraw - mu;
    red[t] = d * d;
    __syncthreads();
    for (int s2 = 64; s2 > 0; s2 >>= 1) { if (t < s2) red[t] += red[t + s2]; __syncthreads(); }
    if (t == 0) var_s = red[0] * (1.f / 128.f);
    __syncthreads();
    float hv = d * rsqrtf(var_s + 1e-5f) * lng[t] + lnb[t];
    hn[t] = hv;
    out_h[g * 128 + t] = hv;
    __syncthreads();

    float accv = bv1[t], acca = ba1[t];
    {
        const float4* hn4 = (const float4*)hn;
        const float4* V1 = (const float4*)(Wv1 + (size_t)t * 128);
        const float4* A1 = (const float4*)(Wa1 + (size_t)t * 128);
        #pragma unroll 4
        for (int k4 = 0; k4 < 32; ++k4) {
            float4 hh = hn4[k4], u;
            u = V1[k4]; accv += hh.x * u.x + hh.y * u.y + hh.z * u.z + hh.w * u.w;
            u = A1[k4]; acca += hh.x * u.x + hh.y * u.y + hh.z * u.z + hh.w * u.w;
        }
    }
    r1[t] = fmaxf(accv, 0.f);
    a1s[t] = fmaxf(acca, 0.f);
    __syncthreads();
    if (t < 2) {
        float s = bv2[t];
        const float4* V2 = (const float4*)(Wv2 + (size_t)t * 128);
        const float4* r4 = (const float4*)r1;
        for (int k4 = 0; k4 < 32; ++k4) { float4 u = V2[k4], rr = r4[k4]; s += rr.x * u.x + rr.y * u.y + rr.z * u.z + rr.w * u.w; }
        val[t] = s;
    }
    if (t < 14) {
        float s = ba2[t];
        const float4* A2 = (const float4*)(Wa2 + (size_t)t * 128);
        const float4* a4 = (const float4*)a1s;
        for (int k4 = 0; k4 < 32; ++k4) { float4 u = A2[k4], aa = a4[k4]; s += aa.x * u.x + aa.y * u.y + aa.z * u.z + aa.w * u.w; }
        adv[t] = s;
    }
    __syncthreads();
    if (t < 14) {
        int o = t & 1;
        float mo = (adv[o] + adv[o + 2] + adv[o + 4] + adv[o + 6] + adv[o + 8] + adv[o + 10] + adv[o + 12]) * (1.f / 7.f);
        float qq = val[o] + adv[t] - mo;
        if (isnan(qq)) qq = 0.f;
        qq = fminf(fmaxf(qq, -100.f), 100.f);
        out_qv[g * 14 + t] = qq;
    }
}

extern "C" void kernel_launch(void* const* d_in, const int* in_sizes, int n_in,
                              void* d_out, int out_size, void* d_ws, size_t ws_size,
                              hipStream_t stream) {
    const float* nf    = (const float*)d_in[0];
    const int*   ei    = (const int*)d_in[1];
    const int*   batch = (const int*)d_in[2];
    const float* w     = (const float*)d_in[3];
    const float* hprev = (const float*)d_in[4];
    const float* cprev = (const float*)d_in[5];
    const float* W_emb = (const float*)d_in[6];  const float* b_emb = (const float*)d_in[7];
    const float* W_g1  = (const float*)d_in[8];  const float* b_g1  = (const float*)d_in[9];
    const float* W_g2  = (const float*)d_in[10]; const float* b_g2  = (const float*)d_in[11];
    const float* Wq    = (const float*)d_in[12]; const float* bq    = (const float*)d_in[13];
    const float* Wk    = (const float*)d_in[14]; const float* bk    = (const float*)d_in[15];
    const float* Wv    = (const float*)d_in[16]; const float* bv    = (const float*)d_in[17];
    const float* Wskip = (const float*)d_in[18]; const float* bskip = (const float*)d_in[19];
    const float* Wgam  = (const float*)d_in[20]; const float* bgam  = (const float*)d_in[21];
    const float* Wbet  = (const float*)d_in[22]; const float* bbet  = (const float*)d_in[23];
    const float* Wih   = (const float*)d_in[24]; const float* bih   = (const float*)d_in[25];
    const float* Whh   = (const float*)d_in[26]; const float* bhh   = (const float*)d_in[27];
    const float* lng   = (const float*)d_in[28]; const float* lnb   = (const float*)d_in[29];
    const float* Wa1   = (const float*)d_in[30]; const float* ba1   = (const float*)d_in[31];
    const float* Wa2   = (const float*)d_in[32]; const float* ba2   = (const float*)d_in[33];
    const float* Wv1   = (const float*)d_in[34]; const float* bv1   = (const float*)d_in[35];
    const float* Wv2   = (const float*)d_in[36]; const float* bv2   = (const float*)d_in[37];

    int N = in_sizes[2];
    int E = in_sizes[1] / 2;
    int B = in_sizes[4] / 128;
    int nb = (N + 1023) / 1024;

    char* p = (char*)d_ws;
    auto alloc = [&](size_t bytes) { char* r = p; p += (bytes + 511) & ~(size_t)511; return r; };
    int*   indeg  = (int*)alloc((size_t)N * 4);
    int*   cursor = (int*)alloc((size_t)N * 4);
    float* gsum   = (float*)alloc((size_t)B * 128 * 4);
    float* cnt    = (float*)alloc((size_t)B * 4);
    size_t zbytes = (size_t)(p - (char*)d_ws);   // region zeroed each call
    int*   off    = (int*)alloc((size_t)(N + 1) * 4);
    int*   col    = (int*)alloc((size_t)E * 4);
    float* dinv   = (float*)alloc((size_t)N * 4);
    int*   bsum   = (int*)alloc((size_t)(nb + 1) * 4);
    int*   bexcl  = (int*)alloc((size_t)(nb + 1) * 4);
    __hip_bfloat16* Wc  = (__hip_bfloat16*)alloc((size_t)6 * 16384 * 2);  // bf16 weights: g1,g2,q,k,v,skip
    __hip_bfloat16* X0b = (__hip_bfloat16*)alloc((size_t)N * 128 * 2);    // x0 / x2
    __hip_bfloat16* X1b = (__hip_bfloat16*)alloc((size_t)N * 128 * 2);    // x1
    ushort_t* XW8 = (ushort_t*)alloc((size_t)N * 128);                    // fp8 xw' (prescaled, x32)
    uint*  KV8 = (uint*)alloc((size_t)N * 256);                           // fp8 [k,v] pairs (x16)
    __hip_bfloat16* Cqb = (__hip_bfloat16*)alloc((size_t)N * 128 * 2);    // q bf16 (x 0.25/16)
    __hip_bfloat16* Bb  = (__hip_bfloat16*)alloc((size_t)N * 128 * 2);    // skip + attn out, bf16
    if ((size_t)(p - (char*)d_ws) > ws_size) return;

    (void)hipMemsetAsync(d_ws, 0, zbytes, stream);

    const __hip_bfloat16* Wg1b  = Wc + 0 * 16384;
    const __hip_bfloat16* Wg2b  = Wc + 1 * 16384;
    const __hip_bfloat16* Wqkvs = Wc + 2 * 16384;   // q,k,v,skip contiguous
    k_cvt6<<<384, 256, 0, stream>>>(W_g1, W_g2, Wq, Wk, Wv, Wskip, Wc);

    int gE = (E + 255) / 256;
    k_count<<<gE, 256, 0, stream>>>(ei, indeg, E);
    k_bsum<<<nb, 256, 0, stream>>>(indeg, bsum, N);
    k_scanb<<<1, 256, 0, stream>>>(bsum, bexcl, off, N, nb, E);
    k_scatter<<<nb, 256, 0, stream>>>(indeg, bexcl, off, dinv, N);
    k_fill<<<gE, 256, 0, stream>>>(ei, off, cursor, col, E);

    int gN = (N + 3) / 4;       // gather kernels: 4 waves/block, 1 node/wave
    int gM = (N + 63) / 64;     // MFMA kernels: 64 rows/block

    k_linear<32, true, true, __hip_bfloat16><<<2048, 256, 0, stream>>>(nf, W_emb, b_emb, X0b, N);   // x0 bf16
    k_lin_mfma_scale<<<gM, 256, 0, stream>>>(X0b, Wg1b, dinv, XW8, N);                              // xw1' fp8
    k_gcn_agg<<<gN, 256, 0, stream>>>(XW8, off, col, dinv, b_g1, (__hip_bfloat162*)X1b, N);         // x1
    k_lin_mfma_scale<<<gM, 256, 0, stream>>>(X1b, Wg2b, dinv, XW8, N);                              // xw2' fp8
    k_gcn_agg<<<gN, 256, 0, stream>>>(XW8, off, col, dinv, b_g2, (__hip_bfloat162*)X0b, N);         // x2

    k_qkvs_mfma<<<gM, 256, 0, stream>>>(X0b, Wqkvs, bq, bk, bv, bskip, Cqb, KV8, Bb, N);            // q,KV,skip
    k_attn<<<gN, 256, 0, stream>>>((const uint*)Cqb, KV8, off, col, (uint*)Bb, N);                  // Bb += attn

    k_pool<<<gM, 128, 0, stream>>>(Bb, batch, gsum, cnt, N);

    float* out_qv = (float*)d_out;
    float* out_h  = out_qv + (size_t)B * 14;
    float* out_c  = out_h + (size_t)B * 128;
    k_final<<<B, 128, 0, stream>>>(gsum, cnt, w, Wgam, bgam, Wbet, bbet, hprev, cprev,
                                   Wih, bih, Whh, bhh, lng, lnb,
                                   Wa1, ba1, Wa2, ba2, Wv1, bv1, Wv2, bv2,
                                   out_qv, out_h, out_c);
}